// Round 1
// baseline (6559.142 us; speedup 1.0000x reference)
//
#include <hip/hip_runtime.h>
#include <math.h>

#define HEADS 3
#define HD 32
#define WIN 7
#define RESH 56
#define RESW 56
#define TOPK 64
#define NW 64
#define WS2 49
#define NKEY 128
#define BATCH 32
#define NPIX 3136
#define SCALE 0.17677669529663687f

// ---------------- workspace layout (bytes) ----------------
#define OFF_IDX0 0ull
#define OFF_IDX1 16384ull
#define OFF_QKV0 32768ull
#define OFF_QKV1 (OFF_QKV0 + 115605504ull)       // 32*3136*288*4
#define OFF_RPB  (OFF_QKV1 + 2359296ull)         // 32*64*288*4
#define OFF_ATT  (OFF_RPB  + 4816896ull)         // 64*3*49*128*4

// ---------------- build neighbor index tables on device ----------------
// Replicates np.argsort(d, kind='stable')[:, :64] with d = sqrt of integer
// squared distance: sort key is (d2, idx) lexicographic, idx ascending scan.
__global__ void build_idx(int* __restrict__ idx0, int* __restrict__ idx1) {
    int w = threadIdx.x;
    if (w >= NW) return;
    int cqh = 7 * (w >> 3) + 3, cqw = 7 * (w & 7) + 3;

    int d2[TOPK];
    int id[TOPK];
    int cnt = 0;
    // level 0: pixels within radius-16 box (provably contains top-64)
    int h0 = cqh - 16; if (h0 < 0) h0 = 0;
    int h1 = cqh + 16; if (h1 > RESH - 1) h1 = RESH - 1;
    int w0 = cqw - 16; if (w0 < 0) w0 = 0;
    int w1 = cqw + 16; if (w1 > RESW - 1) w1 = RESW - 1;
    for (int ph = h0; ph <= h1; ++ph) {
        for (int pw = w0; pw <= w1; ++pw) {
            int dh = cqh - ph, dw = cqw - pw;
            int dd = dh * dh + dw * dw;
            if (cnt == TOPK && dd >= d2[TOPK - 1]) continue;
            int i = (cnt < TOPK) ? cnt : (TOPK - 1);
            while (i > 0 && d2[i - 1] > dd) {
                d2[i] = d2[i - 1]; id[i] = id[i - 1]; --i;
            }
            d2[i] = dd; id[i] = ph * RESW + pw;
            if (cnt < TOPK) ++cnt;
        }
    }
    for (int t = 0; t < TOPK; ++t) idx0[w * TOPK + t] = id[t];

    // level 1: all 64 windows, full stable sort
    cnt = 0;
    for (int p = 0; p < NW; ++p) {
        int kh = 7 * (p >> 3) + 3, kw = 7 * (p & 7) + 3;
        int dh = cqh - kh, dw = cqw - kw;
        int dd = dh * dh + dw * dw;
        int i = cnt;
        while (i > 0 && d2[i - 1] > dd) {
            d2[i] = d2[i - 1]; id[i] = id[i - 1]; --i;
        }
        d2[i] = dd; id[i] = p;
        ++cnt;
    }
    for (int t = 0; t < TOPK; ++t) idx1[w * TOPK + t] = id[t];
}

// ---------------- tiled linear: y[M][NOUT] = x[M][96] @ w[NOUT][96]^T + b ----
// 32 rows per block, 256 threads; thread = 4 rows x TN cols. NOUT = 32*TN.
template <int NOUT, int TN>
__global__ void linear_tiled(const float* __restrict__ x,
                             const float* __restrict__ w,
                             const float* __restrict__ bias,
                             float* __restrict__ y) {
    __shared__ float xs[32 * 96];
    __shared__ float wsT[8 * NOUT];
    int tid = threadIdx.x;
    long long row0 = (long long)blockIdx.x * 32;

    for (int idx = tid; idx < 32 * 96; idx += 256)
        xs[idx] = x[row0 * 96 + idx];

    int tc = (tid & 31) * TN;
    int tr = (tid >> 5) * 4;

    float acc[4][TN];
    for (int j = 0; j < TN; ++j) {
        float bv = bias[tc + j];
        for (int i = 0; i < 4; ++i) acc[i][j] = bv;
    }

    for (int k0 = 0; k0 < 96; k0 += 8) {
        __syncthreads();
        for (int idx = tid; idx < NOUT * 8; idx += 256) {
            int o = idx >> 3, kk = idx & 7;
            wsT[kk * NOUT + o] = w[o * 96 + k0 + kk];
        }
        __syncthreads();
#pragma unroll
        for (int kk = 0; kk < 8; ++kk) {
            float xr[4];
#pragma unroll
            for (int i = 0; i < 4; ++i) xr[i] = xs[(tr + i) * 96 + k0 + kk];
#pragma unroll
            for (int j = 0; j < TN; ++j) {
                float wv = wsT[kk * NOUT + tc + j];
#pragma unroll
                for (int i = 0; i < 4; ++i) acc[i][j] = fmaf(xr[i], wv, acc[i][j]);
            }
        }
    }
    for (int i = 0; i < 4; ++i)
        for (int j = 0; j < TN; ++j)
            y[(row0 + tr + i) * NOUT + tc + j] = acc[i][j];
}

// ---------------- relative position bias MLP ----------------
// rpb[w][h][q][t], t in [0,128): t<64 level0, t>=64 level1
__global__ void rpb_kernel(const int* __restrict__ idx0, const int* __restrict__ idx1,
                           const float* __restrict__ w1_0, const float* __restrict__ b1_0,
                           const float* __restrict__ w2_0, const float* __restrict__ b2_0,
                           const float* __restrict__ w1_1, const float* __restrict__ b1_1,
                           const float* __restrict__ w2_1, const float* __restrict__ b2_1,
                           float* __restrict__ rpb) {
    int gid = blockIdx.x * blockDim.x + threadIdx.x;
    if (gid >= NW * WS2 * NKEY) return;
    int t = gid & 127;
    int q = (gid >> 7) % WS2;
    int w = gid / (WS2 * NKEY);

    int qph = 7 * (w >> 3) + q / 7;
    int qpw = 7 * (w & 7) + q % 7;

    int ckh, ckw;
    const float *w1, *b1, *w2, *b2;
    if (t < TOPK) {
        int p = idx0[w * TOPK + t];
        ckh = p / RESW; ckw = p % RESW;
        w1 = w1_0; b1 = b1_0; w2 = w2_0; b2 = b2_0;
    } else {
        int p = idx1[w * TOPK + (t - TOPK)];
        ckh = 7 * (p >> 3) + 3; ckw = 7 * (p & 7) + 3;
        w1 = w1_1; b1 = b1_1; w2 = w2_1; b2 = b2_1;
    }
    float fh = (float)(qph - ckh) / 56.0f;
    float fw = (float)(qpw - ckw) / 56.0f;

    float o0 = b2[0], o1 = b2[1], o2 = b2[2];
#pragma unroll
    for (int d = 0; d < HD; ++d) {
        float hd = fmaf(w1[d * 2], fh, fmaf(w1[d * 2 + 1], fw, b1[d]));
        hd = fmaxf(hd, 0.0f);
        o0 = fmaf(w2[d], hd, o0);
        o1 = fmaf(w2[HD + d], hd, o1);
        o2 = fmaf(w2[2 * HD + d], hd, o2);
    }
    int base = ((w * HEADS + 0) * WS2 + q) * NKEY + t;
    rpb[base] = o0;
    rpb[base + WS2 * NKEY] = o1;
    rpb[base + 2 * WS2 * NKEY] = o2;
}

// ---------------- attention: one block per (b, w, h) ----------------
__global__ __launch_bounds__(256) void attn_kernel(
        const float* __restrict__ qkv0, const float* __restrict__ qkv1,
        const int* __restrict__ idx0, const int* __restrict__ idx1,
        const float* __restrict__ rpb, float* __restrict__ out) {
    __shared__ float Qs[WS2 * HD];        // 6272 B
    __shared__ float Ks[NKEY * 33];       // 16896 B (+1 pad: kills d-bank conflict)
    __shared__ float Vs[NKEY * 33];       // 16896 B
    __shared__ float S[WS2 * 129];        // 25284 B (row pad 129)

    int blk = blockIdx.x;                 // ((b*64)+w)*3+h
    int h = blk % HEADS;
    int w = (blk / HEADS) & 63;
    int b = blk / (HEADS * NW);
    int tid = threadIdx.x;
    int wi = w >> 3, wj = w & 7;

    for (int idx = tid; idx < WS2 * HD; idx += 256) {
        int q = idx >> 5, d = idx & 31;
        int pix = (wi * 7 + q / 7) * RESW + wj * 7 + q % 7;
        Qs[idx] = qkv0[((size_t)b * NPIX + pix) * 288 + h * HD + d] * SCALE;
    }
    for (int idx = tid; idx < NKEY * HD; idx += 256) {
        int t = idx >> 5, d = idx & 31;
        float kv, vv;
        if (t < TOPK) {
            int p = idx0[w * TOPK + t];
            const float* base = qkv0 + ((size_t)b * NPIX + p) * 288 + 96 + h * HD + d;
            kv = base[0]; vv = base[96];
        } else {
            int p = idx1[w * TOPK + (t - TOPK)];
            const float* base = qkv1 + ((size_t)b * NW + p) * 288 + 96 + h * HD + d;
            kv = base[0]; vv = base[96];
        }
        Ks[t * 33 + d] = kv;
        Vs[t * 33 + d] = vv;
    }
    __syncthreads();

    // scores + bias
    const float* rp = rpb + (size_t)(w * HEADS + h) * WS2 * NKEY;
    for (int s = tid; s < WS2 * NKEY; s += 256) {
        int q = s >> 7, t = s & 127;
        float acc = rp[s];
#pragma unroll
        for (int d = 0; d < HD; ++d) acc = fmaf(Qs[q * HD + d], Ks[t * 33 + d], acc);
        S[q * 129 + t] = acc;
    }
    __syncthreads();

    // softmax over 128 keys; 4 lanes per row
    int g = tid >> 2, l4 = tid & 3;
    if (g < WS2) {
        float m = -1e30f;
        for (int t = l4; t < NKEY; t += 4) m = fmaxf(m, S[g * 129 + t]);
        m = fmaxf(m, __shfl_xor(m, 1));
        m = fmaxf(m, __shfl_xor(m, 2));
        float sum = 0.0f;
        for (int t = l4; t < NKEY; t += 4) {
            float e = expf(S[g * 129 + t] - m);
            S[g * 129 + t] = e;
            sum += e;
        }
        sum += __shfl_xor(sum, 1);
        sum += __shfl_xor(sum, 2);
        float inv = 1.0f / sum;
        for (int t = l4; t < NKEY; t += 4) S[g * 129 + t] *= inv;
    }
    __syncthreads();

    // out = P @ V
    for (int s = tid; s < WS2 * HD; s += 256) {
        int q = s >> 5, d = s & 31;
        float acc = 0.0f;
#pragma unroll 8
        for (int t = 0; t < NKEY; ++t) acc = fmaf(S[q * 129 + t], Vs[t * 33 + d], acc);
        out[(((size_t)b * NW + w) * WS2 + q) * 96 + h * HD + d] = acc;
    }
}

// ---------------- launch ----------------
extern "C" void kernel_launch(void* const* d_in, const int* in_sizes, int n_in,
                              void* d_out, int out_size, void* d_ws, size_t ws_size,
                              hipStream_t stream) {
    const float* x0     = (const float*)d_in[0];
    const float* x1     = (const float*)d_in[1];
    const float* qkv_w  = (const float*)d_in[2];
    const float* qkv_b  = (const float*)d_in[3];
    const float* proj_w = (const float*)d_in[4];
    const float* proj_b = (const float*)d_in[5];
    const float* r0w1   = (const float*)d_in[6];
    const float* r0b1   = (const float*)d_in[7];
    const float* r0w2   = (const float*)d_in[8];
    const float* r0b2   = (const float*)d_in[9];
    const float* r1w1   = (const float*)d_in[10];
    const float* r1b1   = (const float*)d_in[11];
    const float* r1w2   = (const float*)d_in[12];
    const float* r1b2   = (const float*)d_in[13];

    char* ws = (char*)d_ws;
    int*   idx0 = (int*)(ws + OFF_IDX0);
    int*   idx1 = (int*)(ws + OFF_IDX1);
    float* qkv0 = (float*)(ws + OFF_QKV0);
    float* qkv1 = (float*)(ws + OFF_QKV1);
    float* rpb  = (float*)(ws + OFF_RPB);
    float* att  = (float*)(ws + OFF_ATT);

    build_idx<<<1, 64, 0, stream>>>(idx0, idx1);

    // qkv for x0: M = 32*3136 = 100352 rows -> 3136 blocks of 32 rows
    linear_tiled<288, 9><<<3136, 256, 0, stream>>>(x0, qkv_w, qkv_b, qkv0);
    // qkv for x1: M = 32*64 = 2048 rows -> 64 blocks
    linear_tiled<288, 9><<<64, 256, 0, stream>>>(x1, qkv_w, qkv_b, qkv1);

    rpb_kernel<<<(NW * WS2 * NKEY + 255) / 256, 256, 0, stream>>>(
        idx0, idx1, r0w1, r0b1, r0w2, r0b2, r1w1, r1b1, r1w2, r1b2, rpb);

    attn_kernel<<<BATCH * NW * HEADS, 256, 0, stream>>>(qkv0, qkv1, idx0, idx1, rpb, att);

    // proj: M = 100352 rows -> 3136 blocks
    linear_tiled<96, 3><<<3136, 256, 0, stream>>>(att, proj_w, proj_b, (float*)d_out);
}

// Round 2
// 1156.395 us; speedup vs baseline: 5.6721x; 5.6721x over previous
//
#include <hip/hip_runtime.h>
#include <math.h>

#define HEADS 3
#define HD 32
#define WIN 7
#define RESH 56
#define RESW 56
#define TOPK 64
#define NW 64
#define WS2 49
#define NKEY 128
#define BATCH 32
#define NPIX 3136
#define SCALE 0.17677669529663687f

// ---------------- workspace layout (bytes) ----------------
#define OFF_IDX0 0ull
#define OFF_IDX1 16384ull
#define OFF_QKV0 32768ull
#define OFF_QKV1 (OFF_QKV0 + 115605504ull)       // 32*3136*288*4
#define OFF_RPB  (OFF_QKV1 + 2359296ull)         // 32*64*288*4
#define OFF_ATT  (OFF_RPB  + 4816896ull)         // 64*3*49*128*4

// ---------------- build neighbor index tables on device ----------------
// Replicates np.argsort(d, kind='stable')[:, :64].
// Key = (d2 << 12) | pixel_index  reproduces (d2, idx) lexicographic order.
// Radius-6 box provably contains the top-64 (>=64 valid pixels with d<=5
// for every window center; worst case corner = 65).
// Sort arrays live in LDS [entry][thread]: lane t always hits bank t&31 ->
// free 2-way aliasing across the 64-lane wave, no scratch traffic.
__global__ void build_idx(int* __restrict__ idx0, int* __restrict__ idx1) {
    __shared__ int key[TOPK * 64];
    int t = threadIdx.x;
    if (t >= NW) return;
    int cqh = 7 * (t >> 3) + 3, cqw = 7 * (t & 7) + 3;

    // level 0: pixels within radius-6 box
    int cnt = 0;
    for (int dh = -6; dh <= 6; ++dh) {
        int ph = cqh + dh;
        if (ph < 0 || ph >= RESH) continue;
        for (int dw = -6; dw <= 6; ++dw) {
            int pw = cqw + dw;
            if (pw < 0 || pw >= RESW) continue;
            int k = ((dh * dh + dw * dw) << 12) | (ph * RESW + pw);
            if (cnt == TOPK && k >= key[(TOPK - 1) * 64 + t]) continue;
            int i = (cnt < TOPK) ? cnt : (TOPK - 1);
            while (i > 0 && key[(i - 1) * 64 + t] > k) {
                key[i * 64 + t] = key[(i - 1) * 64 + t]; --i;
            }
            key[i * 64 + t] = k;
            if (cnt < TOPK) ++cnt;
        }
    }
    for (int i = 0; i < TOPK; ++i) idx0[t * TOPK + i] = key[i * 64 + t] & 4095;

    // level 1: all 64 windows, full insertion sort (key = (d2<<6)|p)
    for (int p = 0; p < NW; ++p) {
        int kh = 7 * (p >> 3) + 3, kw = 7 * (p & 7) + 3;
        int dh = cqh - kh, dw = cqw - kw;
        int k = ((dh * dh + dw * dw) << 6) | p;
        int i = p;
        while (i > 0 && key[(i - 1) * 64 + t] > k) {
            key[i * 64 + t] = key[(i - 1) * 64 + t]; --i;
        }
        key[i * 64 + t] = k;
    }
    for (int i = 0; i < TOPK; ++i) idx1[t * TOPK + i] = key[i * 64 + t] & 63;
}

// ---------------- tiled linear: y[M][NOUT] = x[M][96] @ w[NOUT][96]^T + b ----
// 32 rows per block, 256 threads; thread = 4 rows x TN cols. NOUT = 32*TN.
template <int NOUT, int TN>
__global__ void linear_tiled(const float* __restrict__ x,
                             const float* __restrict__ w,
                             const float* __restrict__ bias,
                             float* __restrict__ y) {
    __shared__ float xs[32 * 96];
    __shared__ float wsT[8 * NOUT];
    int tid = threadIdx.x;
    long long row0 = (long long)blockIdx.x * 32;

    for (int idx = tid; idx < 32 * 96; idx += 256)
        xs[idx] = x[row0 * 96 + idx];

    int tc = (tid & 31) * TN;
    int tr = (tid >> 5) * 4;

    float acc[4][TN];
    for (int j = 0; j < TN; ++j) {
        float bv = bias[tc + j];
        for (int i = 0; i < 4; ++i) acc[i][j] = bv;
    }

    for (int k0 = 0; k0 < 96; k0 += 8) {
        __syncthreads();
        for (int idx = tid; idx < NOUT * 8; idx += 256) {
            int o = idx >> 3, kk = idx & 7;
            wsT[kk * NOUT + o] = w[o * 96 + k0 + kk];
        }
        __syncthreads();
#pragma unroll
        for (int kk = 0; kk < 8; ++kk) {
            float xr[4];
#pragma unroll
            for (int i = 0; i < 4; ++i) xr[i] = xs[(tr + i) * 96 + k0 + kk];
#pragma unroll
            for (int j = 0; j < TN; ++j) {
                float wv = wsT[kk * NOUT + tc + j];
#pragma unroll
                for (int i = 0; i < 4; ++i) acc[i][j] = fmaf(xr[i], wv, acc[i][j]);
            }
        }
    }
    for (int i = 0; i < 4; ++i)
        for (int j = 0; j < TN; ++j)
            y[(row0 + tr + i) * NOUT + tc + j] = acc[i][j];
}

// ---------------- relative position bias MLP ----------------
// rpb[w][h][q][t], t in [0,128): t<64 level0, t>=64 level1
__global__ void rpb_kernel(const int* __restrict__ idx0, const int* __restrict__ idx1,
                           const float* __restrict__ w1_0, const float* __restrict__ b1_0,
                           const float* __restrict__ w2_0, const float* __restrict__ b2_0,
                           const float* __restrict__ w1_1, const float* __restrict__ b1_1,
                           const float* __restrict__ w2_1, const float* __restrict__ b2_1,
                           float* __restrict__ rpb) {
    int gid = blockIdx.x * blockDim.x + threadIdx.x;
    if (gid >= NW * WS2 * NKEY) return;
    int t = gid & 127;
    int q = (gid >> 7) % WS2;
    int w = gid / (WS2 * NKEY);

    int qph = 7 * (w >> 3) + q / 7;
    int qpw = 7 * (w & 7) + q % 7;

    int ckh, ckw;
    const float *w1, *b1, *w2, *b2;
    if (t < TOPK) {
        int p = idx0[w * TOPK + t];
        ckh = p / RESW; ckw = p % RESW;
        w1 = w1_0; b1 = b1_0; w2 = w2_0; b2 = b2_0;
    } else {
        int p = idx1[w * TOPK + (t - TOPK)];
        ckh = 7 * (p >> 3) + 3; ckw = 7 * (p & 7) + 3;
        w1 = w1_1; b1 = b1_1; w2 = w2_1; b2 = b2_1;
    }
    float fh = (float)(qph - ckh) / 56.0f;
    float fw = (float)(qpw - ckw) / 56.0f;

    float o0 = b2[0], o1 = b2[1], o2 = b2[2];
#pragma unroll
    for (int d = 0; d < HD; ++d) {
        float hd = fmaf(w1[d * 2], fh, fmaf(w1[d * 2 + 1], fw, b1[d]));
        hd = fmaxf(hd, 0.0f);
        o0 = fmaf(w2[d], hd, o0);
        o1 = fmaf(w2[HD + d], hd, o1);
        o2 = fmaf(w2[2 * HD + d], hd, o2);
    }
    int base = ((w * HEADS + 0) * WS2 + q) * NKEY + t;
    rpb[base] = o0;
    rpb[base + WS2 * NKEY] = o1;
    rpb[base + 2 * WS2 * NKEY] = o2;
}

// ---------------- attention: one block per (b, w, h) ----------------
__global__ __launch_bounds__(256) void attn_kernel(
        const float* __restrict__ qkv0, const float* __restrict__ qkv1,
        const int* __restrict__ idx0, const int* __restrict__ idx1,
        const float* __restrict__ rpb, float* __restrict__ out) {
    __shared__ float Qs[WS2 * HD];        // 6272 B
    __shared__ float Ks[NKEY * 33];       // 16896 B (+1 pad: kills d-bank conflict)
    __shared__ float Vs[NKEY * 33];       // 16896 B
    __shared__ float S[WS2 * 129];        // 25284 B (row pad 129)

    int blk = blockIdx.x;                 // ((b*64)+w)*3+h
    int h = blk % HEADS;
    int w = (blk / HEADS) & 63;
    int b = blk / (HEADS * NW);
    int tid = threadIdx.x;
    int wi = w >> 3, wj = w & 7;

    for (int idx = tid; idx < WS2 * HD; idx += 256) {
        int q = idx >> 5, d = idx & 31;
        int pix = (wi * 7 + q / 7) * RESW + wj * 7 + q % 7;
        Qs[idx] = qkv0[((size_t)b * NPIX + pix) * 288 + h * HD + d] * SCALE;
    }
    for (int idx = tid; idx < NKEY * HD; idx += 256) {
        int t = idx >> 5, d = idx & 31;
        float kv, vv;
        if (t < TOPK) {
            int p = idx0[w * TOPK + t];
            const float* base = qkv0 + ((size_t)b * NPIX + p) * 288 + 96 + h * HD + d;
            kv = base[0]; vv = base[96];
        } else {
            int p = idx1[w * TOPK + (t - TOPK)];
            const float* base = qkv1 + ((size_t)b * NW + p) * 288 + 96 + h * HD + d;
            kv = base[0]; vv = base[96];
        }
        Ks[t * 33 + d] = kv;
        Vs[t * 33 + d] = vv;
    }
    __syncthreads();

    // scores + bias
    const float* rp = rpb + (size_t)(w * HEADS + h) * WS2 * NKEY;
    for (int s = tid; s < WS2 * NKEY; s += 256) {
        int q = s >> 7, t = s & 127;
        float acc = rp[s];
#pragma unroll
        for (int d = 0; d < HD; ++d) acc = fmaf(Qs[q * HD + d], Ks[t * 33 + d], acc);
        S[q * 129 + t] = acc;
    }
    __syncthreads();

    // softmax over 128 keys; 4 lanes per row
    int g = tid >> 2, l4 = tid & 3;
    if (g < WS2) {
        float m = -1e30f;
        for (int t = l4; t < NKEY; t += 4) m = fmaxf(m, S[g * 129 + t]);
        m = fmaxf(m, __shfl_xor(m, 1));
        m = fmaxf(m, __shfl_xor(m, 2));
        float sum = 0.0f;
        for (int t = l4; t < NKEY; t += 4) {
            float e = expf(S[g * 129 + t] - m);
            S[g * 129 + t] = e;
            sum += e;
        }
        sum += __shfl_xor(sum, 1);
        sum += __shfl_xor(sum, 2);
        float inv = 1.0f / sum;
        for (int t = l4; t < NKEY; t += 4) S[g * 129 + t] *= inv;
    }
    __syncthreads();

    // out = P @ V
    for (int s = tid; s < WS2 * HD; s += 256) {
        int q = s >> 5, d = s & 31;
        float acc = 0.0f;
#pragma unroll 8
        for (int t = 0; t < NKEY; ++t) acc = fmaf(S[q * 129 + t], Vs[t * 33 + d], acc);
        out[(((size_t)b * NW + w) * WS2 + q) * 96 + h * HD + d] = acc;
    }
}

// ---------------- launch ----------------
extern "C" void kernel_launch(void* const* d_in, const int* in_sizes, int n_in,
                              void* d_out, int out_size, void* d_ws, size_t ws_size,
                              hipStream_t stream) {
    const float* x0     = (const float*)d_in[0];
    const float* x1     = (const float*)d_in[1];
    const float* qkv_w  = (const float*)d_in[2];
    const float* qkv_b  = (const float*)d_in[3];
    const float* proj_w = (const float*)d_in[4];
    const float* proj_b = (const float*)d_in[5];
    const float* r0w1   = (const float*)d_in[6];
    const float* r0b1   = (const float*)d_in[7];
    const float* r0w2   = (const float*)d_in[8];
    const float* r0b2   = (const float*)d_in[9];
    const float* r1w1   = (const float*)d_in[10];
    const float* r1b1   = (const float*)d_in[11];
    const float* r1w2   = (const float*)d_in[12];
    const float* r1b2   = (const float*)d_in[13];

    char* ws = (char*)d_ws;
    int*   idx0 = (int*)(ws + OFF_IDX0);
    int*   idx1 = (int*)(ws + OFF_IDX1);
    float* qkv0 = (float*)(ws + OFF_QKV0);
    float* qkv1 = (float*)(ws + OFF_QKV1);
    float* rpb  = (float*)(ws + OFF_RPB);
    float* att  = (float*)(ws + OFF_ATT);

    build_idx<<<1, 64, 0, stream>>>(idx0, idx1);

    // qkv for x0: M = 32*3136 = 100352 rows -> 3136 blocks of 32 rows
    linear_tiled<288, 9><<<3136, 256, 0, stream>>>(x0, qkv_w, qkv_b, qkv0);
    // qkv for x1: M = 32*64 = 2048 rows -> 64 blocks
    linear_tiled<288, 9><<<64, 256, 0, stream>>>(x1, qkv_w, qkv_b, qkv1);

    rpb_kernel<<<(NW * WS2 * NKEY + 255) / 256, 256, 0, stream>>>(
        idx0, idx1, r0w1, r0b1, r0w2, r0b2, r1w1, r1b1, r1w2, r1b2, rpb);

    attn_kernel<<<BATCH * NW * HEADS, 256, 0, stream>>>(qkv0, qkv1, idx0, idx1, rpb, att);

    // proj: M = 100352 rows -> 3136 blocks
    linear_tiled<96, 3><<<3136, 256, 0, stream>>>(att, proj_w, proj_b, (float*)d_out);
}

// Round 3
// 691.281 us; speedup vs baseline: 9.4884x; 1.6728x over previous
//
#include <hip/hip_runtime.h>
#include <math.h>
#include <limits.h>

#define HEADS 3
#define HD 32
#define WIN 7
#define RESH 56
#define RESW 56
#define TOPK 64
#define NW 64
#define WS2 49
#define NKEY 128
#define BATCH 32
#define NPIX 3136
#define SCALE 0.17677669529663687f

// ---------------- workspace layout (bytes) ----------------
#define OFF_IDX0 0ull
#define OFF_IDX1 16384ull
#define OFF_QKV0 32768ull
#define OFF_QKV1 (OFF_QKV0 + 115605504ull)       // 32*3136*288*4
#define OFF_RPB  (OFF_QKV1 + 2359296ull)         // 32*64*288*4
#define OFF_ATT  (OFF_RPB  + 4816896ull)         // 64*3*49*128*4

// ---------------- build neighbor index tables on device ----------------
// Replicates np.argsort(d, kind='stable')[:, :64] via RANK-SELECTION:
// all keys (d2<<12)|pix are distinct, so final position == rank ==
// #smaller keys. One block per window; O(169^2) independent compares,
// LDS broadcast reads (conflict-free), no dependent shift chains.
// Radius-6 box provably contains the top-64 (>=64 valid pixels with d<=5
// for every window center; worst case corner = 65).
__global__ void build_idx(int* __restrict__ idx0, int* __restrict__ idx1) {
    __shared__ int keys[176];
    int w = blockIdx.x;
    int t = threadIdx.x;
    int cqh = 7 * (w >> 3) + 3, cqw = 7 * (w & 7) + 3;

    // ----- level 0: 13x13 candidate box -----
    if (t < 169) {
        int dh = t / 13 - 6, dw = t % 13 - 6;
        int ph = cqh + dh, pw = cqw + dw;
        int k = INT_MAX;
        if (ph >= 0 && ph < RESH && pw >= 0 && pw < RESW)
            k = ((dh * dh + dw * dw) << 12) | (ph * RESW + pw);
        keys[t] = k;
    }
    __syncthreads();
    if (t < 169 && keys[t] != INT_MAX) {
        int my = keys[t];
        int rank = 0;
        for (int j = 0; j < 169; ++j) rank += (keys[j] < my);
        if (rank < TOPK) idx0[w * TOPK + rank] = my & 4095;
    }
    __syncthreads();

    // ----- level 1: all 64 windows -----
    if (t < NW) {
        int kh = 7 * (t >> 3) + 3, kw = 7 * (t & 7) + 3;
        int dh = cqh - kh, dw = cqw - kw;
        keys[t] = ((dh * dh + dw * dw) << 6) | t;
    }
    __syncthreads();
    if (t < NW) {
        int my = keys[t];
        int rank = 0;
        for (int j = 0; j < NW; ++j) rank += (keys[j] < my);
        idx1[w * TOPK + rank] = my & 63;
    }
}

// ---------------- tiled linear: y[M][NOUT] = x[M][96] @ w[NOUT][96]^T + b ----
// 32 rows per block, 256 threads; thread = 4 rows x TN cols. NOUT = 32*TN.
template <int NOUT, int TN>
__global__ void linear_tiled(const float* __restrict__ x,
                             const float* __restrict__ w,
                             const float* __restrict__ bias,
                             float* __restrict__ y) {
    __shared__ float xs[32 * 96];
    __shared__ float wsT[8 * NOUT];
    int tid = threadIdx.x;
    long long row0 = (long long)blockIdx.x * 32;

    for (int idx = tid; idx < 32 * 96; idx += 256)
        xs[idx] = x[row0 * 96 + idx];

    int tc = (tid & 31) * TN;
    int tr = (tid >> 5) * 4;

    float acc[4][TN];
    for (int j = 0; j < TN; ++j) {
        float bv = bias[tc + j];
        for (int i = 0; i < 4; ++i) acc[i][j] = bv;
    }

    for (int k0 = 0; k0 < 96; k0 += 8) {
        __syncthreads();
        for (int idx = tid; idx < NOUT * 8; idx += 256) {
            int o = idx >> 3, kk = idx & 7;
            wsT[kk * NOUT + o] = w[o * 96 + k0 + kk];
        }
        __syncthreads();
#pragma unroll
        for (int kk = 0; kk < 8; ++kk) {
            float xr[4];
#pragma unroll
            for (int i = 0; i < 4; ++i) xr[i] = xs[(tr + i) * 96 + k0 + kk];
#pragma unroll
            for (int j = 0; j < TN; ++j) {
                float wv = wsT[kk * NOUT + tc + j];
#pragma unroll
                for (int i = 0; i < 4; ++i) acc[i][j] = fmaf(xr[i], wv, acc[i][j]);
            }
        }
    }
    for (int i = 0; i < 4; ++i)
        for (int j = 0; j < TN; ++j)
            y[(row0 + tr + i) * NOUT + tc + j] = acc[i][j];
}

// ---------------- relative position bias MLP ----------------
// rpb[w][h][q][t], t in [0,128): t<64 level0, t>=64 level1
__global__ void rpb_kernel(const int* __restrict__ idx0, const int* __restrict__ idx1,
                           const float* __restrict__ w1_0, const float* __restrict__ b1_0,
                           const float* __restrict__ w2_0, const float* __restrict__ b2_0,
                           const float* __restrict__ w1_1, const float* __restrict__ b1_1,
                           const float* __restrict__ w2_1, const float* __restrict__ b2_1,
                           float* __restrict__ rpb) {
    int gid = blockIdx.x * blockDim.x + threadIdx.x;
    if (gid >= NW * WS2 * NKEY) return;
    int t = gid & 127;
    int q = (gid >> 7) % WS2;
    int w = gid / (WS2 * NKEY);

    int qph = 7 * (w >> 3) + q / 7;
    int qpw = 7 * (w & 7) + q % 7;

    int ckh, ckw;
    const float *w1, *b1, *w2, *b2;
    if (t < TOPK) {
        int p = idx0[w * TOPK + t];
        ckh = p / RESW; ckw = p % RESW;
        w1 = w1_0; b1 = b1_0; w2 = w2_0; b2 = b2_0;
    } else {
        int p = idx1[w * TOPK + (t - TOPK)];
        ckh = 7 * (p >> 3) + 3; ckw = 7 * (p & 7) + 3;
        w1 = w1_1; b1 = b1_1; w2 = w2_1; b2 = b2_1;
    }
    float fh = (float)(qph - ckh) / 56.0f;
    float fw = (float)(qpw - ckw) / 56.0f;

    float o0 = b2[0], o1 = b2[1], o2 = b2[2];
#pragma unroll
    for (int d = 0; d < HD; ++d) {
        float hd = fmaf(w1[d * 2], fh, fmaf(w1[d * 2 + 1], fw, b1[d]));
        hd = fmaxf(hd, 0.0f);
        o0 = fmaf(w2[d], hd, o0);
        o1 = fmaf(w2[HD + d], hd, o1);
        o2 = fmaf(w2[2 * HD + d], hd, o2);
    }
    int base = ((w * HEADS + 0) * WS2 + q) * NKEY + t;
    rpb[base] = o0;
    rpb[base + WS2 * NKEY] = o1;
    rpb[base + 2 * WS2 * NKEY] = o2;
}

// ---------------- attention: one block per (b, w, h) ----------------
__global__ __launch_bounds__(256) void attn_kernel(
        const float* __restrict__ qkv0, const float* __restrict__ qkv1,
        const int* __restrict__ idx0, const int* __restrict__ idx1,
        const float* __restrict__ rpb, float* __restrict__ out) {
    __shared__ float Qs[WS2 * HD];        // 6272 B
    __shared__ float Ks[NKEY * 33];       // 16896 B (+1 pad: kills d-bank conflict)
    __shared__ float Vs[NKEY * 33];       // 16896 B
    __shared__ float S[WS2 * 129];        // 25284 B (row pad 129)

    int blk = blockIdx.x;                 // ((b*64)+w)*3+h
    int h = blk % HEADS;
    int w = (blk / HEADS) & 63;
    int b = blk / (HEADS * NW);
    int tid = threadIdx.x;
    int wi = w >> 3, wj = w & 7;

    for (int idx = tid; idx < WS2 * HD; idx += 256) {
        int q = idx >> 5, d = idx & 31;
        int pix = (wi * 7 + q / 7) * RESW + wj * 7 + q % 7;
        Qs[idx] = qkv0[((size_t)b * NPIX + pix) * 288 + h * HD + d] * SCALE;
    }
    for (int idx = tid; idx < NKEY * HD; idx += 256) {
        int t = idx >> 5, d = idx & 31;
        float kv, vv;
        if (t < TOPK) {
            int p = idx0[w * TOPK + t];
            const float* base = qkv0 + ((size_t)b * NPIX + p) * 288 + 96 + h * HD + d;
            kv = base[0]; vv = base[96];
        } else {
            int p = idx1[w * TOPK + (t - TOPK)];
            const float* base = qkv1 + ((size_t)b * NW + p) * 288 + 96 + h * HD + d;
            kv = base[0]; vv = base[96];
        }
        Ks[t * 33 + d] = kv;
        Vs[t * 33 + d] = vv;
    }
    __syncthreads();

    // scores + bias
    const float* rp = rpb + (size_t)(w * HEADS + h) * WS2 * NKEY;
    for (int s = tid; s < WS2 * NKEY; s += 256) {
        int q = s >> 7, t = s & 127;
        float acc = rp[s];
#pragma unroll
        for (int d = 0; d < HD; ++d) acc = fmaf(Qs[q * HD + d], Ks[t * 33 + d], acc);
        S[q * 129 + t] = acc;
    }
    __syncthreads();

    // softmax over 128 keys; 4 lanes per row
    int g = tid >> 2, l4 = tid & 3;
    if (g < WS2) {
        float m = -1e30f;
        for (int t = l4; t < NKEY; t += 4) m = fmaxf(m, S[g * 129 + t]);
        m = fmaxf(m, __shfl_xor(m, 1));
        m = fmaxf(m, __shfl_xor(m, 2));
        float sum = 0.0f;
        for (int t = l4; t < NKEY; t += 4) {
            float e = expf(S[g * 129 + t] - m);
            S[g * 129 + t] = e;
            sum += e;
        }
        sum += __shfl_xor(sum, 1);
        sum += __shfl_xor(sum, 2);
        float inv = 1.0f / sum;
        for (int t = l4; t < NKEY; t += 4) S[g * 129 + t] *= inv;
    }
    __syncthreads();

    // out = P @ V
    for (int s = tid; s < WS2 * HD; s += 256) {
        int q = s >> 5, d = s & 31;
        float acc = 0.0f;
#pragma unroll 8
        for (int t = 0; t < NKEY; ++t) acc = fmaf(S[q * 129 + t], Vs[t * 33 + d], acc);
        out[(((size_t)b * NW + w) * WS2 + q) * 96 + h * HD + d] = acc;
    }
}

// ---------------- launch ----------------
extern "C" void kernel_launch(void* const* d_in, const int* in_sizes, int n_in,
                              void* d_out, int out_size, void* d_ws, size_t ws_size,
                              hipStream_t stream) {
    const float* x0     = (const float*)d_in[0];
    const float* x1     = (const float*)d_in[1];
    const float* qkv_w  = (const float*)d_in[2];
    const float* qkv_b  = (const float*)d_in[3];
    const float* proj_w = (const float*)d_in[4];
    const float* proj_b = (const float*)d_in[5];
    const float* r0w1   = (const float*)d_in[6];
    const float* r0b1   = (const float*)d_in[7];
    const float* r0w2   = (const float*)d_in[8];
    const float* r0b2   = (const float*)d_in[9];
    const float* r1w1   = (const float*)d_in[10];
    const float* r1b1   = (const float*)d_in[11];
    const float* r1w2   = (const float*)d_in[12];
    const float* r1b2   = (const float*)d_in[13];

    char* ws = (char*)d_ws;
    int*   idx0 = (int*)(ws + OFF_IDX0);
    int*   idx1 = (int*)(ws + OFF_IDX1);
    float* qkv0 = (float*)(ws + OFF_QKV0);
    float* qkv1 = (float*)(ws + OFF_QKV1);
    float* rpb  = (float*)(ws + OFF_RPB);
    float* att  = (float*)(ws + OFF_ATT);

    build_idx<<<NW, 256, 0, stream>>>(idx0, idx1);

    // qkv for x0: M = 32*3136 = 100352 rows -> 3136 blocks of 32 rows
    linear_tiled<288, 9><<<3136, 256, 0, stream>>>(x0, qkv_w, qkv_b, qkv0);
    // qkv for x1: M = 32*64 = 2048 rows -> 64 blocks
    linear_tiled<288, 9><<<64, 256, 0, stream>>>(x1, qkv_w, qkv_b, qkv1);

    rpb_kernel<<<(NW * WS2 * NKEY + 255) / 256, 256, 0, stream>>>(
        idx0, idx1, r0w1, r0b1, r0w2, r0b2, r1w1, r1b1, r1w2, r1b2, rpb);

    attn_kernel<<<BATCH * NW * HEADS, 256, 0, stream>>>(qkv0, qkv1, idx0, idx1, rpb, att);

    // proj: M = 100352 rows -> 3136 blocks
    linear_tiled<96, 3><<<3136, 256, 0, stream>>>(att, proj_w, proj_b, (float*)d_out);
}

// Round 4
// 507.650 us; speedup vs baseline: 12.9206x; 1.3617x over previous
//
#include <hip/hip_runtime.h>
#include <math.h>
#include <limits.h>

#define HEADS 3
#define HD 32
#define WIN 7
#define RESH 56
#define RESW 56
#define TOPK 64
#define NW 64
#define WS2 49
#define NKEY 128
#define BATCH 32
#define NPIX 3136
#define SCALE 0.17677669529663687f

// ---------------- workspace layout (bytes) ----------------
#define OFF_IDX0 0ull
#define OFF_IDX1 16384ull
#define OFF_QKV0 32768ull
#define OFF_QKV1 (OFF_QKV0 + 115605504ull)       // 32*3136*288*4
#define OFF_RPB  (OFF_QKV1 + 2359296ull)         // 32*64*288*4
#define OFF_ATT  (OFF_RPB  + 4816896ull)         // 64*3*49*128*4

// ---------------- build neighbor index tables on device ----------------
// Rank-selection replication of np.argsort(d, kind='stable')[:, :64].
__global__ void build_idx(int* __restrict__ idx0, int* __restrict__ idx1) {
    __shared__ int keys[176];
    int w = blockIdx.x;
    int t = threadIdx.x;
    int cqh = 7 * (w >> 3) + 3, cqw = 7 * (w & 7) + 3;

    if (t < 169) {
        int dh = t / 13 - 6, dw = t % 13 - 6;
        int ph = cqh + dh, pw = cqw + dw;
        int k = INT_MAX;
        if (ph >= 0 && ph < RESH && pw >= 0 && pw < RESW)
            k = ((dh * dh + dw * dw) << 12) | (ph * RESW + pw);
        keys[t] = k;
    }
    __syncthreads();
    if (t < 169 && keys[t] != INT_MAX) {
        int my = keys[t];
        int rank = 0;
        for (int j = 0; j < 169; ++j) rank += (keys[j] < my);
        if (rank < TOPK) idx0[w * TOPK + rank] = my & 4095;
    }
    __syncthreads();

    if (t < NW) {
        int kh = 7 * (t >> 3) + 3, kw = 7 * (t & 7) + 3;
        int dh = cqh - kh, dw = cqw - kw;
        keys[t] = ((dh * dh + dw * dw) << 6) | t;
    }
    __syncthreads();
    if (t < NW) {
        int my = keys[t];
        int rank = 0;
        for (int j = 0; j < NW; ++j) rank += (keys[j] < my);
        idx1[w * TOPK + rank] = my & 63;
    }
}

// ---------------- tiled linear (unchanged this round) ----------------
template <int NOUT, int TN>
__global__ void linear_tiled(const float* __restrict__ x,
                             const float* __restrict__ w,
                             const float* __restrict__ bias,
                             float* __restrict__ y) {
    __shared__ float xs[32 * 96];
    __shared__ float wsT[8 * NOUT];
    int tid = threadIdx.x;
    long long row0 = (long long)blockIdx.x * 32;

    for (int idx = tid; idx < 32 * 96; idx += 256)
        xs[idx] = x[row0 * 96 + idx];

    int tc = (tid & 31) * TN;
    int tr = (tid >> 5) * 4;

    float acc[4][TN];
    for (int j = 0; j < TN; ++j) {
        float bv = bias[tc + j];
        for (int i = 0; i < 4; ++i) acc[i][j] = bv;
    }

    for (int k0 = 0; k0 < 96; k0 += 8) {
        __syncthreads();
        for (int idx = tid; idx < NOUT * 8; idx += 256) {
            int o = idx >> 3, kk = idx & 7;
            wsT[kk * NOUT + o] = w[o * 96 + k0 + kk];
        }
        __syncthreads();
#pragma unroll
        for (int kk = 0; kk < 8; ++kk) {
            float xr[4];
#pragma unroll
            for (int i = 0; i < 4; ++i) xr[i] = xs[(tr + i) * 96 + k0 + kk];
#pragma unroll
            for (int j = 0; j < TN; ++j) {
                float wv = wsT[kk * NOUT + tc + j];
#pragma unroll
                for (int i = 0; i < 4; ++i) acc[i][j] = fmaf(xr[i], wv, acc[i][j]);
            }
        }
    }
    for (int i = 0; i < 4; ++i)
        for (int j = 0; j < TN; ++j)
            y[(row0 + tr + i) * NOUT + tc + j] = acc[i][j];
}

// ---------------- relative position bias MLP (unchanged) ----------------
__global__ void rpb_kernel(const int* __restrict__ idx0, const int* __restrict__ idx1,
                           const float* __restrict__ w1_0, const float* __restrict__ b1_0,
                           const float* __restrict__ w2_0, const float* __restrict__ b2_0,
                           const float* __restrict__ w1_1, const float* __restrict__ b1_1,
                           const float* __restrict__ w2_1, const float* __restrict__ b2_1,
                           float* __restrict__ rpb) {
    int gid = blockIdx.x * blockDim.x + threadIdx.x;
    if (gid >= NW * WS2 * NKEY) return;
    int t = gid & 127;
    int q = (gid >> 7) % WS2;
    int w = gid / (WS2 * NKEY);

    int qph = 7 * (w >> 3) + q / 7;
    int qpw = 7 * (w & 7) + q % 7;

    int ckh, ckw;
    const float *w1, *b1, *w2, *b2;
    if (t < TOPK) {
        int p = idx0[w * TOPK + t];
        ckh = p / RESW; ckw = p % RESW;
        w1 = w1_0; b1 = b1_0; w2 = w2_0; b2 = b2_0;
    } else {
        int p = idx1[w * TOPK + (t - TOPK)];
        ckh = 7 * (p >> 3) + 3; ckw = 7 * (p & 7) + 3;
        w1 = w1_1; b1 = b1_1; w2 = w2_1; b2 = b2_1;
    }
    float fh = (float)(qph - ckh) / 56.0f;
    float fw = (float)(qpw - ckw) / 56.0f;

    float o0 = b2[0], o1 = b2[1], o2 = b2[2];
#pragma unroll
    for (int d = 0; d < HD; ++d) {
        float hd = fmaf(w1[d * 2], fh, fmaf(w1[d * 2 + 1], fw, b1[d]));
        hd = fmaxf(hd, 0.0f);
        o0 = fmaf(w2[d], hd, o0);
        o1 = fmaf(w2[HD + d], hd, o1);
        o2 = fmaf(w2[2 * HD + d], hd, o2);
    }
    int base = ((w * HEADS + 0) * WS2 + q) * NKEY + t;
    rpb[base] = o0;
    rpb[base + WS2 * NKEY] = o1;
    rpb[base + 2 * WS2 * NKEY] = o2;
}

// ---------------- attention v2: register-tiled, K-in-regs ----------------
// One block per (b, w, h), 256 threads (4 waves).
// LDS 48528 B -> 3 blocks/CU (was 65536 -> 2).
// QK^T: thread owns K rows {lane, lane+64} in 64 VGPRs (loaded straight
//       from global; L3-resident), warp wp owns q rows {wp+4i}; Q read as
//       broadcast float4 -> 8 LDS reads per 64 FMA.
// PV:   thread tile 2q x 4d over t-quads: 2 broadcast S-float4 + 4
//       conflict-free V-float4 per 32 FMA.
__global__ __launch_bounds__(256, 3) void attn_kernel(
        const float* __restrict__ qkv0, const float* __restrict__ qkv1,
        const int* __restrict__ idx0, const int* __restrict__ idx1,
        const float* __restrict__ rpb, float* __restrict__ out) {
    __shared__ float Qs[WS2][HD];         // 6272 B, rows 128B-aligned (broadcast reads)
    __shared__ float Vs[NKEY][HD];        // 16384 B, [t][d]: PV reads conflict-free
    __shared__ float S[WS2][132];         // 25872 B, stride 132 words = 528B (16B-aligned)

    int blk = blockIdx.x;                 // ((b*64)+w)*3+h
    int h = blk % HEADS;
    int w = (blk / HEADS) & 63;
    int b = blk / (HEADS * NW);
    int tid = threadIdx.x;
    int wp = tid >> 6, l = tid & 63;
    int wi = w >> 3, wj = w & 7;

    // --- K rows straight into registers (issue early; latency hides under staging)
    int p0 = idx0[w * TOPK + l];
    int p1 = idx1[w * TOPK + l];
    const float4* k0p = reinterpret_cast<const float4*>(
        qkv0 + ((size_t)b * NPIX + p0) * 288 + 96 + h * HD);
    const float4* k1p = reinterpret_cast<const float4*>(
        qkv1 + ((size_t)b * NW + p1) * 288 + 96 + h * HD);
    float4 kr0[8], kr1[8];
#pragma unroll
    for (int j = 0; j < 8; ++j) kr0[j] = k0p[j];
#pragma unroll
    for (int j = 0; j < 8; ++j) kr1[j] = k1p[j];

    // --- stage Q (scaled) into LDS: 392 float4
    for (int u = tid; u < WS2 * 8; u += 256) {
        int q = u >> 3, dq = u & 7;
        int pix = (wi * 7 + q / 7) * RESW + wj * 7 + q % 7;
        float4 v = reinterpret_cast<const float4*>(
            qkv0 + ((size_t)b * NPIX + pix) * 288 + h * HD)[dq];
        v.x *= SCALE; v.y *= SCALE; v.z *= SCALE; v.w *= SCALE;
        reinterpret_cast<float4*>(&Qs[q][0])[dq] = v;
    }
    // --- stage V into LDS: 1024 float4
    for (int u = tid; u < NKEY * 8; u += 256) {
        int t = u >> 3, dq = u & 7;
        float4 v;
        if (t < TOPK) {
            int p = idx0[w * TOPK + t];
            v = reinterpret_cast<const float4*>(
                qkv0 + ((size_t)b * NPIX + p) * 288 + 192 + h * HD)[dq];
        } else {
            int p = idx1[w * TOPK + (t - TOPK)];
            v = reinterpret_cast<const float4*>(
                qkv1 + ((size_t)b * NW + p) * 288 + 192 + h * HD)[dq];
        }
        reinterpret_cast<float4*>(&Vs[t][0])[dq] = v;
    }

    // --- rpb into accumulators (global, coalesced; no LDS dependency)
    const float* rp = rpb + (size_t)(w * HEADS + h) * WS2 * NKEY;
    float acc0[13], acc1[13];
#pragma unroll
    for (int i = 0; i < 13; ++i) {
        int q = wp + 4 * i;
        if (q < WS2) {
            acc0[i] = rp[q * NKEY + l];
            acc1[i] = rp[q * NKEY + TOPK + l];
        }
    }
    __syncthreads();

    // --- S = Q.K^T + rpb
#pragma unroll
    for (int i = 0; i < 13; ++i) {
        int q = wp + 4 * i;
        if (q < WS2) {
            float a0 = acc0[i], a1 = acc1[i];
#pragma unroll
            for (int kq = 0; kq < 8; ++kq) {
                float4 fq = reinterpret_cast<const float4*>(&Qs[q][0])[kq];
                a0 = fmaf(fq.x, kr0[kq].x, a0);
                a0 = fmaf(fq.y, kr0[kq].y, a0);
                a0 = fmaf(fq.z, kr0[kq].z, a0);
                a0 = fmaf(fq.w, kr0[kq].w, a0);
                a1 = fmaf(fq.x, kr1[kq].x, a1);
                a1 = fmaf(fq.y, kr1[kq].y, a1);
                a1 = fmaf(fq.z, kr1[kq].z, a1);
                a1 = fmaf(fq.w, kr1[kq].w, a1);
            }
            S[q][l] = a0;
            S[q][TOPK + l] = a1;
        }
    }
    __syncthreads();

    // --- softmax over 128 keys; 4 lanes per row (strided reads: conflict-free)
    int g = tid >> 2, l4 = tid & 3;
    if (g < WS2) {
        float m = -1e30f;
        for (int t = l4; t < NKEY; t += 4) m = fmaxf(m, S[g][t]);
        m = fmaxf(m, __shfl_xor(m, 1));
        m = fmaxf(m, __shfl_xor(m, 2));
        float sum = 0.0f;
        for (int t = l4; t < NKEY; t += 4) {
            float e = expf(S[g][t] - m);
            S[g][t] = e;
            sum += e;
        }
        sum += __shfl_xor(sum, 1);
        sum += __shfl_xor(sum, 2);
        float inv = 1.0f / sum;
        for (int t = l4; t < NKEY; t += 4) S[g][t] *= inv;
    }
    __syncthreads();

    // --- out = P @ V : thread tile 2q x 4d, 200 active threads
    if (tid < 200) {
        int qtile = tid >> 3, dtile = tid & 7;
        int q0 = qtile * 2;
        bool two = (q0 + 1 < WS2);
        int q1 = two ? q0 + 1 : q0;
        float4 a0 = {0.f, 0.f, 0.f, 0.f};
        float4 a1 = {0.f, 0.f, 0.f, 0.f};
#pragma unroll 4
        for (int tq = 0; tq < 32; ++tq) {
            float4 s0 = reinterpret_cast<const float4*>(&S[q0][0])[tq];
            float4 s1 = reinterpret_cast<const float4*>(&S[q1][0])[tq];
            float4 v0 = reinterpret_cast<const float4*>(&Vs[4 * tq + 0][0])[dtile];
            float4 v1 = reinterpret_cast<const float4*>(&Vs[4 * tq + 1][0])[dtile];
            float4 v2 = reinterpret_cast<const float4*>(&Vs[4 * tq + 2][0])[dtile];
            float4 v3 = reinterpret_cast<const float4*>(&Vs[4 * tq + 3][0])[dtile];
            a0.x = fmaf(s0.x, v0.x, a0.x); a0.y = fmaf(s0.x, v0.y, a0.y);
            a0.z = fmaf(s0.x, v0.z, a0.z); a0.w = fmaf(s0.x, v0.w, a0.w);
            a0.x = fmaf(s0.y, v1.x, a0.x); a0.y = fmaf(s0.y, v1.y, a0.y);
            a0.z = fmaf(s0.y, v1.z, a0.z); a0.w = fmaf(s0.y, v1.w, a0.w);
            a0.x = fmaf(s0.z, v2.x, a0.x); a0.y = fmaf(s0.z, v2.y, a0.y);
            a0.z = fmaf(s0.z, v2.z, a0.z); a0.w = fmaf(s0.z, v2.w, a0.w);
            a0.x = fmaf(s0.w, v3.x, a0.x); a0.y = fmaf(s0.w, v3.y, a0.y);
            a0.z = fmaf(s0.w, v3.z, a0.z); a0.w = fmaf(s0.w, v3.w, a0.w);
            a1.x = fmaf(s1.x, v0.x, a1.x); a1.y = fmaf(s1.x, v0.y, a1.y);
            a1.z = fmaf(s1.x, v0.z, a1.z); a1.w = fmaf(s1.x, v0.w, a1.w);
            a1.x = fmaf(s1.y, v1.x, a1.x); a1.y = fmaf(s1.y, v1.y, a1.y);
            a1.z = fmaf(s1.y, v1.z, a1.z); a1.w = fmaf(s1.y, v1.w, a1.w);
            a1.x = fmaf(s1.z, v2.x, a1.x); a1.y = fmaf(s1.z, v2.y, a1.y);
            a1.z = fmaf(s1.z, v2.z, a1.z); a1.w = fmaf(s1.z, v2.w, a1.w);
            a1.x = fmaf(s1.w, v3.x, a1.x); a1.y = fmaf(s1.w, v3.y, a1.y);
            a1.z = fmaf(s1.w, v3.z, a1.z); a1.w = fmaf(s1.w, v3.w, a1.w);
        }
        size_t ob = (((size_t)b * NW + w) * WS2 + q0) * 96 + h * HD + dtile * 4;
        *reinterpret_cast<float4*>(out + ob) = a0;
        if (two) *reinterpret_cast<float4*>(out + ob + 96) = a1;
    }
}

// ---------------- launch ----------------
extern "C" void kernel_launch(void* const* d_in, const int* in_sizes, int n_in,
                              void* d_out, int out_size, void* d_ws, size_t ws_size,
                              hipStream_t stream) {
    const float* x0     = (const float*)d_in[0];
    const float* x1     = (const float*)d_in[1];
    const float* qkv_w  = (const float*)d_in[2];
    const float* qkv_b  = (const float*)d_in[3];
    const float* proj_w = (const float*)d_in[4];
    const float* proj_b = (const float*)d_in[5];
    const float* r0w1   = (const float*)d_in[6];
    const float* r0b1   = (const float*)d_in[7];
    const float* r0w2   = (const float*)d_in[8];
    const float* r0b2   = (const float*)d_in[9];
    const float* r1w1   = (const float*)d_in[10];
    const float* r1b1   = (const float*)d_in[11];
    const float* r1w2   = (const float*)d_in[12];
    const float* r1b2   = (const float*)d_in[13];

    char* ws = (char*)d_ws;
    int*   idx0 = (int*)(ws + OFF_IDX0);
    int*   idx1 = (int*)(ws + OFF_IDX1);
    float* qkv0 = (float*)(ws + OFF_QKV0);
    float* qkv1 = (float*)(ws + OFF_QKV1);
    float* rpb  = (float*)(ws + OFF_RPB);
    float* att  = (float*)(ws + OFF_ATT);

    build_idx<<<NW, 256, 0, stream>>>(idx0, idx1);

    linear_tiled<288, 9><<<3136, 256, 0, stream>>>(x0, qkv_w, qkv_b, qkv0);
    linear_tiled<288, 9><<<64, 256, 0, stream>>>(x1, qkv_w, qkv_b, qkv1);

    rpb_kernel<<<(NW * WS2 * NKEY + 255) / 256, 256, 0, stream>>>(
        idx0, idx1, r0w1, r0b1, r0w2, r0b2, r1w1, r1b1, r1w2, r1b2, rpb);

    attn_kernel<<<BATCH * NW * HEADS, 256, 0, stream>>>(qkv0, qkv1, idx0, idx1, rpb, att);

    linear_tiled<96, 3><<<3136, 256, 0, stream>>>(att, proj_w, proj_b, (float*)d_out);
}

// Round 5
// 428.584 us; speedup vs baseline: 15.3042x; 1.1845x over previous
//
#include <hip/hip_runtime.h>
#include <math.h>
#include <limits.h>

#define HEADS 3
#define HD 32
#define WIN 7
#define RESH 56
#define RESW 56
#define TOPK 64
#define NW 64
#define WS2 49
#define NKEY 128
#define BATCH 32
#define NPIX 3136
#define SCALE 0.17677669529663687f

// ---------------- workspace layout (bytes) ----------------
#define OFF_IDX0 0ull
#define OFF_IDX1 16384ull
#define OFF_QKV0 32768ull
#define OFF_QKV1 (OFF_QKV0 + 115605504ull)       // 32*3136*288*4
#define OFF_RPB  (OFF_QKV1 + 2359296ull)         // 32*64*288*4
#define OFF_ATT  (OFF_RPB  + 4816896ull)         // 64*3*49*128*4

// ---------------- build neighbor index tables on device ----------------
// Rank-selection replication of np.argsort(d, kind='stable')[:, :64].
__global__ void build_idx(int* __restrict__ idx0, int* __restrict__ idx1) {
    __shared__ int keys[176];
    int w = blockIdx.x;
    int t = threadIdx.x;
    int cqh = 7 * (w >> 3) + 3, cqw = 7 * (w & 7) + 3;

    if (t < 169) {
        int dh = t / 13 - 6, dw = t % 13 - 6;
        int ph = cqh + dh, pw = cqw + dw;
        int k = INT_MAX;
        if (ph >= 0 && ph < RESH && pw >= 0 && pw < RESW)
            k = ((dh * dh + dw * dw) << 12) | (ph * RESW + pw);
        keys[t] = k;
    }
    __syncthreads();
    if (t < 169 && keys[t] != INT_MAX) {
        int my = keys[t];
        int rank = 0;
        for (int j = 0; j < 169; ++j) rank += (keys[j] < my);
        if (rank < TOPK) idx0[w * TOPK + rank] = my & 4095;
    }
    __syncthreads();

    if (t < NW) {
        int kh = 7 * (t >> 3) + 3, kw = 7 * (t & 7) + 3;
        int dh = cqh - kh, dw = cqw - kw;
        keys[t] = ((dh * dh + dw * dw) << 6) | t;
    }
    __syncthreads();
    if (t < NW) {
        int my = keys[t];
        int rank = 0;
        for (int j = 0; j < NW; ++j) rank += (keys[j] < my);
        idx1[w * TOPK + rank] = my & 63;
    }
}

// ---------------- linear v2: y[M][NT*96] = x[M][96] @ w^T + b ----------------
// BM=128 x BN=96 per block, 256 threads (16n x 16m), thread tile TM=8 x TN=6.
// Stage x-tile + w-tile ONCE, single barrier, K=96 register-blocked loop.
// Bank audit: xs[128][100], thread rows tm+16i -> read banks 4*tm (free);
// wt[k][n] [96][97] -> read banks k+6*tn, all 16 distinct (free).
template <int NT>
__global__ __launch_bounds__(256, 1) void linear_v2(const float* __restrict__ x,
                                                    const float* __restrict__ w,
                                                    const float* __restrict__ bias,
                                                    float* __restrict__ y) {
    __shared__ float xs[128][100];   // 51200 B (b128-aligned rows: 400 B)
    __shared__ float wt[96][97];     // 37248 B, wt[k][n]
    const int NOUT = NT * 96;
    int tid = threadIdx.x;
    long long m0 = (long long)blockIdx.x * 128;
    int n0 = blockIdx.y * 96;

    // stage x: 128 rows x 24 float4 = 3072 f4, coalesced reads, b128 LDS writes
#pragma unroll
    for (int it = 0; it < 12; ++it) {
        int id = tid + 256 * it;
        int mm = id / 24, c = id % 24;
        float4 v = *reinterpret_cast<const float4*>(x + (m0 + mm) * 96 + 4 * c);
        *reinterpret_cast<float4*>(&xs[mm][4 * c]) = v;
    }
    // stage w transposed: 96 rows x 24 f4; scalar LDS writes <=2-way conflicts
#pragma unroll
    for (int it = 0; it < 9; ++it) {
        int id = tid + 256 * it;
        int nn = id / 24, c = id % 24;
        float4 v = *reinterpret_cast<const float4*>(w + (long long)(n0 + nn) * 96 + 4 * c);
        wt[4 * c + 0][nn] = v.x;
        wt[4 * c + 1][nn] = v.y;
        wt[4 * c + 2][nn] = v.z;
        wt[4 * c + 3][nn] = v.w;
    }

    int tn = tid & 15, tm = tid >> 4;
    int nb = tn * 6;

    float acc[8][6];
#pragma unroll
    for (int j = 0; j < 6; ++j) {
        float bv = bias[n0 + nb + j];
#pragma unroll
        for (int i = 0; i < 8; ++i) acc[i][j] = bv;
    }
    __syncthreads();

#pragma unroll 8
    for (int k = 0; k < 96; ++k) {
        float xr[8];
#pragma unroll
        for (int i = 0; i < 8; ++i) xr[i] = xs[tm + 16 * i][k];
#pragma unroll
        for (int j = 0; j < 6; ++j) {
            float wv = wt[k][nb + j];
#pragma unroll
            for (int i = 0; i < 8; ++i) acc[i][j] = fmaf(xr[i], wv, acc[i][j]);
        }
    }

#pragma unroll
    for (int i = 0; i < 8; ++i) {
        long long base = (m0 + tm + 16 * i) * NOUT + n0 + nb;
        float2 p0 = {acc[i][0], acc[i][1]};
        float2 p1 = {acc[i][2], acc[i][3]};
        float2 p2 = {acc[i][4], acc[i][5]};
        *reinterpret_cast<float2*>(y + base + 0) = p0;
        *reinterpret_cast<float2*>(y + base + 2) = p1;
        *reinterpret_cast<float2*>(y + base + 4) = p2;
    }
}

// ---------------- relative position bias MLP (unchanged) ----------------
__global__ void rpb_kernel(const int* __restrict__ idx0, const int* __restrict__ idx1,
                           const float* __restrict__ w1_0, const float* __restrict__ b1_0,
                           const float* __restrict__ w2_0, const float* __restrict__ b2_0,
                           const float* __restrict__ w1_1, const float* __restrict__ b1_1,
                           const float* __restrict__ w2_1, const float* __restrict__ b2_1,
                           float* __restrict__ rpb) {
    int gid = blockIdx.x * blockDim.x + threadIdx.x;
    if (gid >= NW * WS2 * NKEY) return;
    int t = gid & 127;
    int q = (gid >> 7) % WS2;
    int w = gid / (WS2 * NKEY);

    int qph = 7 * (w >> 3) + q / 7;
    int qpw = 7 * (w & 7) + q % 7;

    int ckh, ckw;
    const float *w1, *b1, *w2, *b2;
    if (t < TOPK) {
        int p = idx0[w * TOPK + t];
        ckh = p / RESW; ckw = p % RESW;
        w1 = w1_0; b1 = b1_0; w2 = w2_0; b2 = b2_0;
    } else {
        int p = idx1[w * TOPK + (t - TOPK)];
        ckh = 7 * (p >> 3) + 3; ckw = 7 * (p & 7) + 3;
        w1 = w1_1; b1 = b1_1; w2 = w2_1; b2 = b2_1;
    }
    float fh = (float)(qph - ckh) / 56.0f;
    float fw = (float)(qpw - ckw) / 56.0f;

    float o0 = b2[0], o1 = b2[1], o2 = b2[2];
#pragma unroll
    for (int d = 0; d < HD; ++d) {
        float hd = fmaf(w1[d * 2], fh, fmaf(w1[d * 2 + 1], fw, b1[d]));
        hd = fmaxf(hd, 0.0f);
        o0 = fmaf(w2[d], hd, o0);
        o1 = fmaf(w2[HD + d], hd, o1);
        o2 = fmaf(w2[2 * HD + d], hd, o2);
    }
    int base = ((w * HEADS + 0) * WS2 + q) * NKEY + t;
    rpb[base] = o0;
    rpb[base + WS2 * NKEY] = o1;
    rpb[base + 2 * WS2 * NKEY] = o2;
}

// ---------------- attention (unchanged this round) ----------------
__global__ __launch_bounds__(256, 3) void attn_kernel(
        const float* __restrict__ qkv0, const float* __restrict__ qkv1,
        const int* __restrict__ idx0, const int* __restrict__ idx1,
        const float* __restrict__ rpb, float* __restrict__ out) {
    __shared__ float Qs[WS2][HD];
    __shared__ float Vs[NKEY][HD];
    __shared__ float S[WS2][132];

    int blk = blockIdx.x;                 // ((b*64)+w)*3+h
    int h = blk % HEADS;
    int w = (blk / HEADS) & 63;
    int b = blk / (HEADS * NW);
    int tid = threadIdx.x;
    int wp = tid >> 6, l = tid & 63;
    int wi = w >> 3, wj = w & 7;

    int p0 = idx0[w * TOPK + l];
    int p1 = idx1[w * TOPK + l];
    const float4* k0p = reinterpret_cast<const float4*>(
        qkv0 + ((size_t)b * NPIX + p0) * 288 + 96 + h * HD);
    const float4* k1p = reinterpret_cast<const float4*>(
        qkv1 + ((size_t)b * NW + p1) * 288 + 96 + h * HD);
    float4 kr0[8], kr1[8];
#pragma unroll
    for (int j = 0; j < 8; ++j) kr0[j] = k0p[j];
#pragma unroll
    for (int j = 0; j < 8; ++j) kr1[j] = k1p[j];

    for (int u = tid; u < WS2 * 8; u += 256) {
        int q = u >> 3, dq = u & 7;
        int pix = (wi * 7 + q / 7) * RESW + wj * 7 + q % 7;
        float4 v = reinterpret_cast<const float4*>(
            qkv0 + ((size_t)b * NPIX + pix) * 288 + h * HD)[dq];
        v.x *= SCALE; v.y *= SCALE; v.z *= SCALE; v.w *= SCALE;
        reinterpret_cast<float4*>(&Qs[q][0])[dq] = v;
    }
    for (int u = tid; u < NKEY * 8; u += 256) {
        int t = u >> 3, dq = u & 7;
        float4 v;
        if (t < TOPK) {
            int p = idx0[w * TOPK + t];
            v = reinterpret_cast<const float4*>(
                qkv0 + ((size_t)b * NPIX + p) * 288 + 192 + h * HD)[dq];
        } else {
            int p = idx1[w * TOPK + (t - TOPK)];
            v = reinterpret_cast<const float4*>(
                qkv1 + ((size_t)b * NW + p) * 288 + 192 + h * HD)[dq];
        }
        reinterpret_cast<float4*>(&Vs[t][0])[dq] = v;
    }

    const float* rp = rpb + (size_t)(w * HEADS + h) * WS2 * NKEY;
    float acc0[13], acc1[13];
#pragma unroll
    for (int i = 0; i < 13; ++i) {
        int q = wp + 4 * i;
        if (q < WS2) {
            acc0[i] = rp[q * NKEY + l];
            acc1[i] = rp[q * NKEY + TOPK + l];
        }
    }
    __syncthreads();

#pragma unroll
    for (int i = 0; i < 13; ++i) {
        int q = wp + 4 * i;
        if (q < WS2) {
            float a0 = acc0[i], a1 = acc1[i];
#pragma unroll
            for (int kq = 0; kq < 8; ++kq) {
                float4 fq = reinterpret_cast<const float4*>(&Qs[q][0])[kq];
                a0 = fmaf(fq.x, kr0[kq].x, a0);
                a0 = fmaf(fq.y, kr0[kq].y, a0);
                a0 = fmaf(fq.z, kr0[kq].z, a0);
                a0 = fmaf(fq.w, kr0[kq].w, a0);
                a1 = fmaf(fq.x, kr1[kq].x, a1);
                a1 = fmaf(fq.y, kr1[kq].y, a1);
                a1 = fmaf(fq.z, kr1[kq].z, a1);
                a1 = fmaf(fq.w, kr1[kq].w, a1);
            }
            S[q][l] = a0;
            S[q][TOPK + l] = a1;
        }
    }
    __syncthreads();

    int g = tid >> 2, l4 = tid & 3;
    if (g < WS2) {
        float m = -1e30f;
        for (int t = l4; t < NKEY; t += 4) m = fmaxf(m, S[g][t]);
        m = fmaxf(m, __shfl_xor(m, 1));
        m = fmaxf(m, __shfl_xor(m, 2));
        float sum = 0.0f;
        for (int t = l4; t < NKEY; t += 4) {
            float e = expf(S[g][t] - m);
            S[g][t] = e;
            sum += e;
        }
        sum += __shfl_xor(sum, 1);
        sum += __shfl_xor(sum, 2);
        float inv = 1.0f / sum;
        for (int t = l4; t < NKEY; t += 4) S[g][t] *= inv;
    }
    __syncthreads();

    if (tid < 200) {
        int qtile = tid >> 3, dtile = tid & 7;
        int q0 = qtile * 2;
        bool two = (q0 + 1 < WS2);
        int q1 = two ? q0 + 1 : q0;
        float4 a0 = {0.f, 0.f, 0.f, 0.f};
        float4 a1 = {0.f, 0.f, 0.f, 0.f};
#pragma unroll 4
        for (int tq = 0; tq < 32; ++tq) {
            float4 s0 = reinterpret_cast<const float4*>(&S[q0][0])[tq];
            float4 s1 = reinterpret_cast<const float4*>(&S[q1][0])[tq];
            float4 v0 = reinterpret_cast<const float4*>(&Vs[4 * tq + 0][0])[dtile];
            float4 v1 = reinterpret_cast<const float4*>(&Vs[4 * tq + 1][0])[dtile];
            float4 v2 = reinterpret_cast<const float4*>(&Vs[4 * tq + 2][0])[dtile];
            float4 v3 = reinterpret_cast<const float4*>(&Vs[4 * tq + 3][0])[dtile];
            a0.x = fmaf(s0.x, v0.x, a0.x); a0.y = fmaf(s0.x, v0.y, a0.y);
            a0.z = fmaf(s0.x, v0.z, a0.z); a0.w = fmaf(s0.x, v0.w, a0.w);
            a0.x = fmaf(s0.y, v1.x, a0.x); a0.y = fmaf(s0.y, v1.y, a0.y);
            a0.z = fmaf(s0.y, v1.z, a0.z); a0.w = fmaf(s0.y, v1.w, a0.w);
            a0.x = fmaf(s0.z, v2.x, a0.x); a0.y = fmaf(s0.z, v2.y, a0.y);
            a0.z = fmaf(s0.z, v2.z, a0.z); a0.w = fmaf(s0.z, v2.w, a0.w);
            a0.x = fmaf(s0.w, v3.x, a0.x); a0.y = fmaf(s0.w, v3.y, a0.y);
            a0.z = fmaf(s0.w, v3.z, a0.z); a0.w = fmaf(s0.w, v3.w, a0.w);
            a1.x = fmaf(s1.x, v0.x, a1.x); a1.y = fmaf(s1.x, v0.y, a1.y);
            a1.z = fmaf(s1.x, v0.z, a1.z); a1.w = fmaf(s1.x, v0.w, a1.w);
            a1.x = fmaf(s1.y, v1.x, a1.x); a1.y = fmaf(s1.y, v1.y, a1.y);
            a1.z = fmaf(s1.y, v1.z, a1.z); a1.w = fmaf(s1.y, v1.w, a1.w);
            a1.x = fmaf(s1.z, v2.x, a1.x); a1.y = fmaf(s1.z, v2.y, a1.y);
            a1.z = fmaf(s1.z, v2.z, a1.z); a1.w = fmaf(s1.z, v2.w, a1.w);
            a1.x = fmaf(s1.w, v3.x, a1.x); a1.y = fmaf(s1.w, v3.y, a1.y);
            a1.z = fmaf(s1.w, v3.z, a1.z); a1.w = fmaf(s1.w, v3.w, a1.w);
        }
        size_t ob = (((size_t)b * NW + w) * WS2 + q0) * 96 + h * HD + dtile * 4;
        *reinterpret_cast<float4*>(out + ob) = a0;
        if (two) *reinterpret_cast<float4*>(out + ob + 96) = a1;
    }
}

// ---------------- launch ----------------
extern "C" void kernel_launch(void* const* d_in, const int* in_sizes, int n_in,
                              void* d_out, int out_size, void* d_ws, size_t ws_size,
                              hipStream_t stream) {
    const float* x0     = (const float*)d_in[0];
    const float* x1     = (const float*)d_in[1];
    const float* qkv_w  = (const float*)d_in[2];
    const float* qkv_b  = (const float*)d_in[3];
    const float* proj_w = (const float*)d_in[4];
    const float* proj_b = (const float*)d_in[5];
    const float* r0w1   = (const float*)d_in[6];
    const float* r0b1   = (const float*)d_in[7];
    const float* r0w2   = (const float*)d_in[8];
    const float* r0b2   = (const float*)d_in[9];
    const float* r1w1   = (const float*)d_in[10];
    const float* r1b1   = (const float*)d_in[11];
    const float* r1w2   = (const float*)d_in[12];
    const float* r1b2   = (const float*)d_in[13];

    char* ws = (char*)d_ws;
    int*   idx0 = (int*)(ws + OFF_IDX0);
    int*   idx1 = (int*)(ws + OFF_IDX1);
    float* qkv0 = (float*)(ws + OFF_QKV0);
    float* qkv1 = (float*)(ws + OFF_QKV1);
    float* rpb  = (float*)(ws + OFF_RPB);
    float* att  = (float*)(ws + OFF_ATT);

    build_idx<<<NW, 256, 0, stream>>>(idx0, idx1);

    // qkv for x0: M=100352 -> 784 m-tiles x 3 n-tiles
    linear_v2<3><<<dim3(784, 3), 256, 0, stream>>>(x0, qkv_w, qkv_b, qkv0);
    // qkv for x1: M=2048 -> 16 m-tiles x 3 n-tiles
    linear_v2<3><<<dim3(16, 3), 256, 0, stream>>>(x1, qkv_w, qkv_b, qkv1);

    rpb_kernel<<<(NW * WS2 * NKEY + 255) / 256, 256, 0, stream>>>(
        idx0, idx1, r0w1, r0b1, r0w2, r0b2, r1w1, r1b1, r1w2, r1b2, rpb);

    attn_kernel<<<BATCH * NW * HEADS, 256, 0, stream>>>(qkv0, qkv1, idx0, idx1, rpb, att);

    // proj: M=100352 -> 784 m-tiles x 1 n-tile
    linear_v2<1><<<dim3(784, 1), 256, 0, stream>>>(att, proj_w, proj_b, (float*)d_out);
}

// Round 7
// 384.619 us; speedup vs baseline: 17.0536x; 1.1143x over previous
//
#include <hip/hip_runtime.h>
#include <hip/hip_bf16.h>
#include <math.h>
#include <limits.h>

#define HEADS 3
#define HD 32
#define WIN 7
#define RESH 56
#define RESW 56
#define TOPK 64
#define NW 64
#define WS2 49
#define NKEY 128
#define BATCH 32
#define NPIX 3136
#define SCALE 0.17677669529663687f

typedef __attribute__((ext_vector_type(8))) short short8;
typedef __attribute__((ext_vector_type(4))) float f32x4;

// ---------------- workspace layout (bytes) ----------------
#define OFF_IDX0 0ull
#define OFF_IDX1 16384ull
#define OFF_QKV0 32768ull
#define OFF_QKV1 (OFF_QKV0 + 115605504ull)       // 32*3136*288*4
#define OFF_RPB  (OFF_QKV1 + 2359296ull)         // 32*64*288*4
#define OFF_ATT  (OFF_RPB  + 4816896ull)         // 32*64*49*96*4 = 38535168
#define OFF_WQ   (OFF_ATT  + 38535168ull)        // 288*96*2
#define OFF_WP   (OFF_WQ   + 55296ull)           // 96*96*2

// f32 -> bf16 bits, round-to-nearest-even (matches HW cvt for normals)
__device__ inline short f2bf(float f) {
    unsigned u = __float_as_uint(f);
    unsigned r = (u + 0x7fffu + ((u >> 16) & 1u)) >> 16;
    return (short)r;
}

// ---------------- build neighbor index tables on device ----------------
// Rank-selection replication of np.argsort(d, kind='stable')[:, :64].
__global__ void build_idx(int* __restrict__ idx0, int* __restrict__ idx1) {
    __shared__ int keys[176];
    int w = blockIdx.x;
    int t = threadIdx.x;
    int cqh = 7 * (w >> 3) + 3, cqw = 7 * (w & 7) + 3;

    if (t < 169) {
        int dh = t / 13 - 6, dw = t % 13 - 6;
        int ph = cqh + dh, pw = cqw + dw;
        int k = INT_MAX;
        if (ph >= 0 && ph < RESH && pw >= 0 && pw < RESW)
            k = ((dh * dh + dw * dw) << 12) | (ph * RESW + pw);
        keys[t] = k;
    }
    __syncthreads();
    if (t < 169 && keys[t] != INT_MAX) {
        int my = keys[t];
        int rank = 0;
        for (int j = 0; j < 169; ++j) rank += (keys[j] < my);
        if (rank < TOPK) idx0[w * TOPK + rank] = my & 4095;
    }
    __syncthreads();

    if (t < NW) {
        int kh = 7 * (t >> 3) + 3, kw = 7 * (t & 7) + 3;
        int dh = cqh - kh, dw = cqw - kw;
        keys[t] = ((dh * dh + dw * dw) << 6) | t;
    }
    __syncthreads();
    if (t < NW) {
        int my = keys[t];
        int rank = 0;
        for (int j = 0; j < NW; ++j) rank += (keys[j] < my);
        idx1[w * TOPK + rank] = my & 63;
    }
}

// ---------------- weight conversion f32 -> bf16 ----------------
__global__ void cvt_weights(const float* __restrict__ qkv_w,
                            const float* __restrict__ proj_w,
                            short* __restrict__ wq, short* __restrict__ wp) {
    int i = blockIdx.x * 256 + threadIdx.x;
    if (i < 288 * 96) wq[i] = f2bf(qkv_w[i]);
    if (i < 96 * 96)  wp[i] = f2bf(proj_w[i]);
}

// ---------------- MFMA linear ----------------
// y[M][NOUT] = x[M][96] @ w^T + b, NOUT = 96*NT (qkv NT=3 -> 288, proj NT=1 -> 96)
// 384 threads = 6 independent waves; wave wv owns cols [wv*16*NT, +16*NT).
// B-frags (bf16 weights) live in VGPRs for the whole block; A converted
// f32->bf16 on the fly. Zero LDS, zero barriers.
// Fragment layout (16x16x32): A row=lane&15, k=(lane>>4)*8+j;
// B col=lane&15, same k; D col=lane&15, row=(lane>>4)*4+reg  [m89].
template <int NT, int MT>
__global__ __launch_bounds__(384) void linear_mfma(const float* __restrict__ x,
                                                   const short* __restrict__ wb,
                                                   const float* __restrict__ bias,
                                                   float* __restrict__ y) {
    const int NOUT = 96 * NT;
    int wv = threadIdx.x >> 6;        // 0..5
    int l  = threadIdx.x & 63;
    int cl = l & 15;                  // col / row-in-tile
    int kch = l >> 4;                 // 0..3 k-chunk
    int n0 = wv * 16 * NT;

    // preload B fragments + bias (held for whole block lifetime)
    short8 bfr[NT][3];
    float bv[NT];
#pragma unroll
    for (int nt = 0; nt < NT; ++nt) {
        int n = n0 + nt * 16 + cl;
        bv[nt] = bias[n];
#pragma unroll
        for (int ks = 0; ks < 3; ++ks)
            bfr[nt][ks] = *reinterpret_cast<const short8*>(wb + n * 96 + ks * 32 + kch * 8);
    }

    size_t m0 = (size_t)blockIdx.x * (MT * 16);
#pragma unroll 2
    for (int mt = 0; mt < MT; ++mt) {
        size_t mrow = m0 + mt * 16 + cl;
        const float* xp = x + mrow * 96 + kch * 8;
        short8 af[3];
#pragma unroll
        for (int ks = 0; ks < 3; ++ks) {
            float4 u0 = *reinterpret_cast<const float4*>(xp + ks * 32);
            float4 u1 = *reinterpret_cast<const float4*>(xp + ks * 32 + 4);
            short8 a;
            a[0] = f2bf(u0.x); a[1] = f2bf(u0.y); a[2] = f2bf(u0.z); a[3] = f2bf(u0.w);
            a[4] = f2bf(u1.x); a[5] = f2bf(u1.y); a[6] = f2bf(u1.z); a[7] = f2bf(u1.w);
            af[ks] = a;
        }
#pragma unroll
        for (int nt = 0; nt < NT; ++nt) {
            f32x4 acc = {bv[nt], bv[nt], bv[nt], bv[nt]};
#pragma unroll
            for (int ks = 0; ks < 3; ++ks)
                acc = __builtin_amdgcn_mfma_f32_16x16x32_bf16(af[ks], bfr[nt][ks], acc, 0, 0, 0);
            size_t rb = m0 + mt * 16 + kch * 4;
            int c = n0 + nt * 16 + cl;
#pragma unroll
            for (int r = 0; r < 4; ++r)
                y[(rb + r) * NOUT + c] = acc[r];
        }
    }
}

// ---------------- relative position bias MLP (unchanged) ----------------
__global__ void rpb_kernel(const int* __restrict__ idx0, const int* __restrict__ idx1,
                           const float* __restrict__ w1_0, const float* __restrict__ b1_0,
                           const float* __restrict__ w2_0, const float* __restrict__ b2_0,
                           const float* __restrict__ w1_1, const float* __restrict__ b1_1,
                           const float* __restrict__ w2_1, const float* __restrict__ b2_1,
                           float* __restrict__ rpb) {
    int gid = blockIdx.x * blockDim.x + threadIdx.x;
    if (gid >= NW * WS2 * NKEY) return;
    int t = gid & 127;
    int q = (gid >> 7) % WS2;
    int w = gid / (WS2 * NKEY);

    int qph = 7 * (w >> 3) + q / 7;
    int qpw = 7 * (w & 7) + q % 7;

    int ckh, ckw;
    const float *w1, *b1, *w2, *b2;
    if (t < TOPK) {
        int p = idx0[w * TOPK + t];
        ckh = p / RESW; ckw = p % RESW;
        w1 = w1_0; b1 = b1_0; w2 = w2_0; b2 = b2_0;
    } else {
        int p = idx1[w * TOPK + (t - TOPK)];
        ckh = 7 * (p >> 3) + 3; ckw = 7 * (p & 7) + 3;
        w1 = w1_1; b1 = b1_1; w2 = w2_1; b2 = b2_1;
    }
    float fh = (float)(qph - ckh) / 56.0f;
    float fw = (float)(qpw - ckw) / 56.0f;

    float o0 = b2[0], o1 = b2[1], o2 = b2[2];
#pragma unroll
    for (int d = 0; d < HD; ++d) {
        float hd = fmaf(w1[d * 2], fh, fmaf(w1[d * 2 + 1], fw, b1[d]));
        hd = fmaxf(hd, 0.0f);
        o0 = fmaf(w2[d], hd, o0);
        o1 = fmaf(w2[HD + d], hd, o1);
        o2 = fmaf(w2[2 * HD + d], hd, o2);
    }
    int base = ((w * HEADS + 0) * WS2 + q) * NKEY + t;
    rpb[base] = o0;
    rpb[base + WS2 * NKEY] = o1;
    rpb[base + 2 * WS2 * NKEY] = o2;
}

// ---------------- attention (unchanged this round) ----------------
__global__ __launch_bounds__(256, 3) void attn_kernel(
        const float* __restrict__ qkv0, const float* __restrict__ qkv1,
        const int* __restrict__ idx0, const int* __restrict__ idx1,
        const float* __restrict__ rpb, float* __restrict__ out) {
    __shared__ float Qs[WS2][HD];
    __shared__ float Vs[NKEY][HD];
    __shared__ float S[WS2][132];

    int blk = blockIdx.x;                 // ((b*64)+w)*3+h
    int h = blk % HEADS;
    int w = (blk / HEADS) & 63;
    int b = blk / (HEADS * NW);
    int tid = threadIdx.x;
    int wp = tid >> 6, l = tid & 63;
    int wi = w >> 3, wj = w & 7;

    int p0 = idx0[w * TOPK + l];
    int p1 = idx1[w * TOPK + l];
    const float4* k0p = reinterpret_cast<const float4*>(
        qkv0 + ((size_t)b * NPIX + p0) * 288 + 96 + h * HD);
    const float4* k1p = reinterpret_cast<const float4*>(
        qkv1 + ((size_t)b * NW + p1) * 288 + 96 + h * HD);
    float4 kr0[8], kr1[8];
#pragma unroll
    for (int j = 0; j < 8; ++j) kr0[j] = k0p[j];
#pragma unroll
    for (int j = 0; j < 8; ++j) kr1[j] = k1p[j];

    for (int u = tid; u < WS2 * 8; u += 256) {
        int q = u >> 3, dq = u & 7;
        int pix = (wi * 7 + q / 7) * RESW + wj * 7 + q % 7;
        float4 v = reinterpret_cast<const float4*>(
            qkv0 + ((size_t)b * NPIX + pix) * 288 + h * HD)[dq];
        v.x *= SCALE; v.y *= SCALE; v.z *= SCALE; v.w *= SCALE;
        reinterpret_cast<float4*>(&Qs[q][0])[dq] = v;
    }
    for (int u = tid; u < NKEY * 8; u += 256) {
        int t = u >> 3, dq = u & 7;
        float4 v;
        if (t < TOPK) {
            int p = idx0[w * TOPK + t];
            v = reinterpret_cast<const float4*>(
                qkv0 + ((size_t)b * NPIX + p) * 288 + 192 + h * HD)[dq];
        } else {
            int p = idx1[w * TOPK + (t - TOPK)];
            v = reinterpret_cast<const float4*>(
                qkv1 + ((size_t)b * NW + p) * 288 + 192 + h * HD)[dq];
        }
        reinterpret_cast<float4*>(&Vs[t][0])[dq] = v;
    }

    const float* rp = rpb + (size_t)(w * HEADS + h) * WS2 * NKEY;
    float acc0[13], acc1[13];
#pragma unroll
    for (int i = 0; i < 13; ++i) {
        int q = wp + 4 * i;
        if (q < WS2) {
            acc0[i] = rp[q * NKEY + l];
            acc1[i] = rp[q * NKEY + TOPK + l];
        }
    }
    __syncthreads();

#pragma unroll
    for (int i = 0; i < 13; ++i) {
        int q = wp + 4 * i;
        if (q < WS2) {
            float a0 = acc0[i], a1 = acc1[i];
#pragma unroll
            for (int kq = 0; kq < 8; ++kq) {
                float4 fq = reinterpret_cast<const float4*>(&Qs[q][0])[kq];
                a0 = fmaf(fq.x, kr0[kq].x, a0);
                a0 = fmaf(fq.y, kr0[kq].y, a0);
                a0 = fmaf(fq.z, kr0[kq].z, a0);
                a0 = fmaf(fq.w, kr0[kq].w, a0);
                a1 = fmaf(fq.x, kr1[kq].x, a1);
                a1 = fmaf(fq.y, kr1[kq].y, a1);
                a1 = fmaf(fq.z, kr1[kq].z, a1);
                a1 = fmaf(fq.w, kr1[kq].w, a1);
            }
            S[q][l] = a0;
            S[q][TOPK + l] = a1;
        }
    }
    __syncthreads();

    int g = tid >> 2, l4 = tid & 3;
    if (g < WS2) {
        float m = -1e30f;
        for (int t = l4; t < NKEY; t += 4) m = fmaxf(m, S[g][t]);
        m = fmaxf(m, __shfl_xor(m, 1));
        m = fmaxf(m, __shfl_xor(m, 2));
        float sum = 0.0f;
        for (int t = l4; t < NKEY; t += 4) {
            float e = expf(S[g][t] - m);
            S[g][t] = e;
            sum += e;
        }
        sum += __shfl_xor(sum, 1);
        sum += __shfl_xor(sum, 2);
        float inv = 1.0f / sum;
        for (int t = l4; t < NKEY; t += 4) S[g][t] *= inv;
    }
    __syncthreads();

    if (tid < 200) {
        int qtile = tid >> 3, dtile = tid & 7;
        int q0 = qtile * 2;
        bool two = (q0 + 1 < WS2);
        int q1 = two ? q0 + 1 : q0;
        float4 a0 = {0.f, 0.f, 0.f, 0.f};
        float4 a1 = {0.f, 0.f, 0.f, 0.f};
#pragma unroll 4
        for (int tq = 0; tq < 32; ++tq) {
            float4 s0 = reinterpret_cast<const float4*>(&S[q0][0])[tq];
            float4 s1 = reinterpret_cast<const float4*>(&S[q1][0])[tq];
            float4 v0 = reinterpret_cast<const float4*>(&Vs[4 * tq + 0][0])[dtile];
            float4 v1 = reinterpret_cast<const float4*>(&Vs[4 * tq + 1][0])[dtile];
            float4 v2 = reinterpret_cast<const float4*>(&Vs[4 * tq + 2][0])[dtile];
            float4 v3 = reinterpret_cast<const float4*>(&Vs[4 * tq + 3][0])[dtile];
            a0.x = fmaf(s0.x, v0.x, a0.x); a0.y = fmaf(s0.x, v0.y, a0.y);
            a0.z = fmaf(s0.x, v0.z, a0.z); a0.w = fmaf(s0.x, v0.w, a0.w);
            a0.x = fmaf(s0.y, v1.x, a0.x); a0.y = fmaf(s0.y, v1.y, a0.y);
            a0.z = fmaf(s0.y, v1.z, a0.z); a0.w = fmaf(s0.y, v1.w, a0.w);
            a0.x = fmaf(s0.z, v2.x, a0.x); a0.y = fmaf(s0.z, v2.y, a0.y);
            a0.z = fmaf(s0.z, v2.z, a0.z); a0.w = fmaf(s0.z, v2.w, a0.w);
            a0.x = fmaf(s0.w, v3.x, a0.x); a0.y = fmaf(s0.w, v3.y, a0.y);
            a0.z = fmaf(s0.w, v3.z, a0.z); a0.w = fmaf(s0.w, v3.w, a0.w);
            a1.x = fmaf(s1.x, v0.x, a1.x); a1.y = fmaf(s1.x, v0.y, a1.y);
            a1.z = fmaf(s1.x, v0.z, a1.z); a1.w = fmaf(s1.x, v0.w, a1.w);
            a1.x = fmaf(s1.y, v1.x, a1.x); a1.y = fmaf(s1.y, v1.y, a1.y);
            a1.z = fmaf(s1.y, v1.z, a1.z); a1.w = fmaf(s1.y, v1.w, a1.w);
            a1.x = fmaf(s1.z, v2.x, a1.x); a1.y = fmaf(s1.z, v2.y, a1.y);
            a1.z = fmaf(s1.z, v2.z, a1.z); a1.w = fmaf(s1.z, v2.w, a1.w);
            a1.x = fmaf(s1.w, v3.x, a1.x); a1.y = fmaf(s1.w, v3.y, a1.y);
            a1.z = fmaf(s1.w, v3.z, a1.z); a1.w = fmaf(s1.w, v3.w, a1.w);
        }
        size_t ob = (((size_t)b * NW + w) * WS2 + q0) * 96 + h * HD + dtile * 4;
        *reinterpret_cast<float4*>(out + ob) = a0;
        if (two) *reinterpret_cast<float4*>(out + ob + 96) = a1;
    }
}

// ---------------- launch ----------------
extern "C" void kernel_launch(void* const* d_in, const int* in_sizes, int n_in,
                              void* d_out, int out_size, void* d_ws, size_t ws_size,
                              hipStream_t stream) {
    const float* x0     = (const float*)d_in[0];
    const float* x1     = (const float*)d_in[1];
    const float* qkv_w  = (const float*)d_in[2];
    const float* qkv_b  = (const float*)d_in[3];
    const float* proj_w = (const float*)d_in[4];
    const float* proj_b = (const float*)d_in[5];
    const float* r0w1   = (const float*)d_in[6];
    const float* r0b1   = (const float*)d_in[7];
    const float* r0w2   = (const float*)d_in[8];
    const float* r0b2   = (const float*)d_in[9];
    const float* r1w1   = (const float*)d_in[10];
    const float* r1b1   = (const float*)d_in[11];
    const float* r1w2   = (const float*)d_in[12];
    const float* r1b2   = (const float*)d_in[13];

    char* ws = (char*)d_ws;
    int*   idx0 = (int*)(ws + OFF_IDX0);
    int*   idx1 = (int*)(ws + OFF_IDX1);
    float* qkv0 = (float*)(ws + OFF_QKV0);
    float* qkv1 = (float*)(ws + OFF_QKV1);
    float* rpb  = (float*)(ws + OFF_RPB);
    float* att  = (float*)(ws + OFF_ATT);
    short* wqb  = (short*)(ws + OFF_WQ);
    short* wpb  = (short*)(ws + OFF_WP);

    build_idx<<<NW, 256, 0, stream>>>(idx0, idx1);
    cvt_weights<<<108, 256, 0, stream>>>(qkv_w, proj_w, wqb, wpb);

    // qkv for x0: M=100352 -> 784 blocks x 128 rows
    linear_mfma<3, 8><<<784, 384, 0, stream>>>(x0, wqb, qkv_b, qkv0);
    // qkv for x1: M=2048 -> 16 blocks
    linear_mfma<3, 8><<<16, 384, 0, stream>>>(x1, wqb, qkv_b, qkv1);

    rpb_kernel<<<(NW * WS2 * NKEY + 255) / 256, 256, 0, stream>>>(
        idx0, idx1, r0w1, r0b1, r0w2, r0b2, r1w1, r1b1, r1w2, r1b2, rpb);

    attn_kernel<<<BATCH * NW * HEADS, 256, 0, stream>>>(qkv0, qkv1, idx0, idx1, rpb, att);

    // proj: M=100352 -> 784 blocks
    linear_mfma<1, 8><<<784, 384, 0, stream>>>(att, wpb, proj_b, (float*)d_out);
}

// Round 9
// 234.312 us; speedup vs baseline: 27.9932x; 1.6415x over previous
//
#include <hip/hip_runtime.h>
#include <hip/hip_bf16.h>
#include <math.h>
#include <limits.h>

#define HEADS 3
#define HD 32
#define WIN 7
#define RESH 56
#define RESW 56
#define TOPK 64
#define NW 64
#define WS2 49
#define NKEY 128
#define BATCH 32
#define NPIX 3136
#define SCALE 0.17677669529663687f

typedef __attribute__((ext_vector_type(8))) short short8;
typedef __attribute__((ext_vector_type(4))) float f32x4;

// ---------------- workspace layout (bytes) ----------------
// qkv0/qkv1/att are bf16 now (half traffic); rpb stays fp32.
#define OFF_IDX0 0ull
#define OFF_IDX1 16384ull
#define OFF_QKV0 32768ull                         // 32*3136*288*2 = 57802752
#define OFF_QKV1 57835520ull                      // 32*64*288*2   = 1179648
#define OFF_RPB  59015168ull                      // 64*3*49*128*4 = 4816896
#define OFF_ATT  63832064ull                      // 32*64*49*96*2 = 19267584
#define OFF_WQ   83099648ull                      // 288*96*2
#define OFF_WP   83154944ull                      // 96*96*2

// f32 -> bf16 bits, round-to-nearest-even
__device__ inline short f2bf(float f) {
    unsigned u = __float_as_uint(f);
    unsigned r = (u + 0x7fffu + ((u >> 16) & 1u)) >> 16;
    return (short)r;
}

// ---------------- build neighbor index tables (unchanged) ----------------
__global__ void build_idx(int* __restrict__ idx0, int* __restrict__ idx1) {
    __shared__ int keys[176];
    int w = blockIdx.x;
    int t = threadIdx.x;
    int cqh = 7 * (w >> 3) + 3, cqw = 7 * (w & 7) + 3;

    if (t < 169) {
        int dh = t / 13 - 6, dw = t % 13 - 6;
        int ph = cqh + dh, pw = cqw + dw;
        int k = INT_MAX;
        if (ph >= 0 && ph < RESH && pw >= 0 && pw < RESW)
            k = ((dh * dh + dw * dw) << 12) | (ph * RESW + pw);
        keys[t] = k;
    }
    __syncthreads();
    if (t < 169 && keys[t] != INT_MAX) {
        int my = keys[t];
        int rank = 0;
        for (int j = 0; j < 169; ++j) rank += (keys[j] < my);
        if (rank < TOPK) idx0[w * TOPK + rank] = my & 4095;
    }
    __syncthreads();

    if (t < NW) {
        int kh = 7 * (t >> 3) + 3, kw = 7 * (t & 7) + 3;
        int dh = cqh - kh, dw = cqw - kw;
        keys[t] = ((dh * dh + dw * dw) << 6) | t;
    }
    __syncthreads();
    if (t < NW) {
        int my = keys[t];
        int rank = 0;
        for (int j = 0; j < NW; ++j) rank += (keys[j] < my);
        idx1[w * TOPK + rank] = my & 63;
    }
}

// ---------------- weight conversion f32 -> bf16 ----------------
__global__ void cvt_weights(const float* __restrict__ qkv_w,
                            const float* __restrict__ proj_w,
                            short* __restrict__ wq, short* __restrict__ wp) {
    int i = blockIdx.x * 256 + threadIdx.x;
    if (i < 288 * 96) wq[i] = f2bf(qkv_w[i]);
    if (i < 96 * 96)  wp[i] = f2bf(proj_w[i]);
}

// ---------------- MFMA linear (templated on in/out dtype) ----------------
// y[M][NOUT] = x[M][96] @ w^T + b. 6 waves, B-frags resident in VGPRs,
// zero LDS / zero barriers. Validated layout [m89] (round-7 pass).
template <int NT, int MT, bool INBF, bool OUTBF>
__global__ __launch_bounds__(384) void linear_mfma(const void* __restrict__ xv,
                                                   const short* __restrict__ wb,
                                                   const float* __restrict__ bias,
                                                   void* __restrict__ yv) {
    const int NOUT = 96 * NT;
    const float* xf = (const float*)xv;
    const short* xb = (const short*)xv;
    float* yf = (float*)yv;
    short* yb = (short*)yv;
    int wv = threadIdx.x >> 6;
    int l  = threadIdx.x & 63;
    int cl = l & 15;
    int kch = l >> 4;
    int n0 = wv * 16 * NT;

    short8 bfr[NT][3];
    float bv[NT];
#pragma unroll
    for (int nt = 0; nt < NT; ++nt) {
        int n = n0 + nt * 16 + cl;
        bv[nt] = bias[n];
#pragma unroll
        for (int ks = 0; ks < 3; ++ks)
            bfr[nt][ks] = *reinterpret_cast<const short8*>(wb + n * 96 + ks * 32 + kch * 8);
    }

    size_t m0 = (size_t)blockIdx.x * (MT * 16);
#pragma unroll 2
    for (int mt = 0; mt < MT; ++mt) {
        size_t mrow = m0 + mt * 16 + cl;
        short8 af[3];
        if constexpr (INBF) {
            const short* xp = xb + mrow * 96 + kch * 8;
#pragma unroll
            for (int ks = 0; ks < 3; ++ks)
                af[ks] = *reinterpret_cast<const short8*>(xp + ks * 32);
        } else {
            const float* xp = xf + mrow * 96 + kch * 8;
#pragma unroll
            for (int ks = 0; ks < 3; ++ks) {
                float4 u0 = *reinterpret_cast<const float4*>(xp + ks * 32);
                float4 u1 = *reinterpret_cast<const float4*>(xp + ks * 32 + 4);
                short8 a;
                a[0] = f2bf(u0.x); a[1] = f2bf(u0.y); a[2] = f2bf(u0.z); a[3] = f2bf(u0.w);
                a[4] = f2bf(u1.x); a[5] = f2bf(u1.y); a[6] = f2bf(u1.z); a[7] = f2bf(u1.w);
                af[ks] = a;
            }
        }
#pragma unroll
        for (int nt = 0; nt < NT; ++nt) {
            f32x4 acc = {bv[nt], bv[nt], bv[nt], bv[nt]};
#pragma unroll
            for (int ks = 0; ks < 3; ++ks)
                acc = __builtin_amdgcn_mfma_f32_16x16x32_bf16(af[ks], bfr[nt][ks], acc, 0, 0, 0);
            size_t rb = m0 + mt * 16 + kch * 4;
            int c = n0 + nt * 16 + cl;
#pragma unroll
            for (int r = 0; r < 4; ++r) {
                if constexpr (OUTBF) yb[(rb + r) * NOUT + c] = f2bf(acc[r]);
                else                 yf[(rb + r) * NOUT + c] = acc[r];
            }
        }
    }
}

// ---------------- relative position bias MLP (unchanged) ----------------
__global__ void rpb_kernel(const int* __restrict__ idx0, const int* __restrict__ idx1,
                           const float* __restrict__ w1_0, const float* __restrict__ b1_0,
                           const float* __restrict__ w2_0, const float* __restrict__ b2_0,
                           const float* __restrict__ w1_1, const float* __restrict__ b1_1,
                           const float* __restrict__ w2_1, const float* __restrict__ b2_1,
                           float* __restrict__ rpb) {
    int gid = blockIdx.x * blockDim.x + threadIdx.x;
    if (gid >= NW * WS2 * NKEY) return;
    int t = gid & 127;
    int q = (gid >> 7) % WS2;
    int w = gid / (WS2 * NKEY);

    int qph = 7 * (w >> 3) + q / 7;
    int qpw = 7 * (w & 7) + q % 7;

    int ckh, ckw;
    const float *w1, *b1, *w2, *b2;
    if (t < TOPK) {
        int p = idx0[w * TOPK + t];
        ckh = p / RESW; ckw = p % RESW;
        w1 = w1_0; b1 = b1_0; w2 = w2_0; b2 = b2_0;
    } else {
        int p = idx1[w * TOPK + (t - TOPK)];
        ckh = 7 * (p >> 3) + 3; ckw = 7 * (p & 7) + 3;
        w1 = w1_1; b1 = b1_1; w2 = w2_1; b2 = b2_1;
    }
    float fh = (float)(qph - ckh) / 56.0f;
    float fw = (float)(qpw - ckw) / 56.0f;

    float o0 = b2[0], o1 = b2[1], o2 = b2[2];
#pragma unroll
    for (int d = 0; d < HD; ++d) {
        float hd = fmaf(w1[d * 2], fh, fmaf(w1[d * 2 + 1], fw, b1[d]));
        hd = fmaxf(hd, 0.0f);
        o0 = fmaf(w2[d], hd, o0);
        o1 = fmaf(w2[HD + d], hd, o1);
        o2 = fmaf(w2[2 * HD + d], hd, o2);
    }
    int base = ((w * HEADS + 0) * WS2 + q) * NKEY + t;
    rpb[base] = o0;
    rpb[base + WS2 * NKEY] = o1;
    rpb[base + 2 * WS2 * NKEY] = o2;
}

// ---------------- attention v3: full MFMA ----------------
// Block per (b,w,h), 256 threads = 4 waves; wave wv owns q-tile [wv*16, +16).
// QK^T: 8 MFMA (S = SCALE*acc + rpb in epilogue). Softmax in registers
// (D rows are lane-local; 4x shfl_xor over the 16-lane col group).
// P unnormalized bf16 -> LDS (XOR swizzle); PV: 8 MFMA; inv applied to O.
// LDS swizzles audited conflict-free (chunk-rotate for Q/K, XOR for P/Vt).
__global__ __launch_bounds__(256) void attn_mfma(
        const short* __restrict__ qkv0, const short* __restrict__ qkv1,
        const int* __restrict__ idx0, const int* __restrict__ idx1,
        const float* __restrict__ rpb, short* __restrict__ out) {
    __shared__ __align__(16) short Qb[64 * 32];    // 4 KB, chunk-rotated
    __shared__ __align__(16) short Kb[128 * 32];   // 8 KB, chunk-rotated
    __shared__ __align__(16) short Vt[32 * 128];   // 8 KB, transposed + XOR swz
    __shared__ __align__(16) short Pb[64 * 128];   // 16 KB, XOR swz

    int blk = blockIdx.x;                 // ((b*64)+w)*3+h
    int h = blk % HEADS;
    int w = (blk / HEADS) & 63;
    int b = blk / (HEADS * NW);
    int tid = threadIdx.x;
    int wv = tid >> 6, l = tid & 63;
    int cl = l & 15, kch = l >> 4;
    int wi = w >> 3, wj = w & 7;

    // --- stage Q (64 rows x 4 chunks; rows >=49 zero)
    {
        int q = tid >> 2, c = tid & 3;
        short8 v = {0, 0, 0, 0, 0, 0, 0, 0};
        if (q < WS2) {
            int pix = (wi * 7 + q / 7) * RESW + wj * 7 + q % 7;
            v = *reinterpret_cast<const short8*>(
                qkv0 + ((size_t)b * NPIX + pix) * 288 + h * 32 + c * 8);
        }
        *reinterpret_cast<short8*>(Qb + q * 32 + (((c + (q >> 1)) & 3) << 3)) = v;
    }
    // --- stage K (c-fast: coalesced global, rotate-swizzled LDS, conflict-free)
#pragma unroll
    for (int i = 0; i < 2; ++i) {
        int u = tid + 256 * i;
        int k = u >> 2, c = u & 3;
        const short* src = (k < TOPK)
            ? qkv0 + ((size_t)b * NPIX + idx0[w * TOPK + k]) * 288 + 96 + h * 32
            : qkv1 + ((size_t)b * NW + idx1[w * TOPK + k - TOPK]) * 288 + 96 + h * 32;
        short8 kv = *reinterpret_cast<const short8*>(src + c * 8);
        *reinterpret_cast<short8*>(Kb + k * 32 + (((c + (k >> 1)) & 3) << 3)) = kv;
    }
    // --- stage V transposed (k-fast keeps the b16 scatter <=2-way)
#pragma unroll
    for (int i = 0; i < 2; ++i) {
        int u = tid + 256 * i;
        int k = u & 127, c = u >> 7;
        const short* src = (k < TOPK)
            ? qkv0 + ((size_t)b * NPIX + idx0[w * TOPK + k]) * 288 + 192 + h * 32
            : qkv1 + ((size_t)b * NW + idx1[w * TOPK + k - TOPK]) * 288 + 192 + h * 32;
        short8 vv = *reinterpret_cast<const short8*>(src + c * 8);
#pragma unroll
        for (int jj = 0; jj < 8; ++jj) {
            int d = c * 8 + jj;
            Vt[d * 128 + (((k >> 3) ^ (d & 7)) << 3) + (k & 7)] = vv[jj];
        }
    }
    // --- rpb into registers (coalesced fp32 reads)
    const float* rp = rpb + (size_t)(w * HEADS + h) * WS2 * NKEY;
    int qbase = wv * 16 + kch * 4;
    float rv[8][4];
#pragma unroll
    for (int nt = 0; nt < 8; ++nt)
#pragma unroll
        for (int r = 0; r < 4; ++r) {
            int q = qbase + r;
            rv[nt][r] = (q < WS2) ? rp[q * NKEY + nt * 16 + cl] : 0.0f;
        }
    __syncthreads();

    // --- QK^T: S[q][key], q-tile wv
    int qa = wv * 16 + cl;
    short8 qf = *reinterpret_cast<const short8*>(
        Qb + qa * 32 + (((kch + (qa >> 1)) & 3) << 3));
    float s[8][4];
#pragma unroll
    for (int nt = 0; nt < 8; ++nt) {
        int key = nt * 16 + cl;
        short8 kf = *reinterpret_cast<const short8*>(
            Kb + key * 32 + (((kch + (key >> 1)) & 3) << 3));
        f32x4 a = {0.f, 0.f, 0.f, 0.f};
        a = __builtin_amdgcn_mfma_f32_16x16x32_bf16(qf, kf, a, 0, 0, 0);
#pragma unroll
        for (int r = 0; r < 4; ++r) s[nt][r] = fmaf(a[r], SCALE, rv[nt][r]);
    }

    // --- in-register softmax over 128 keys (rows q = qbase + r)
    float inv[4], p[8][4];
#pragma unroll
    for (int r = 0; r < 4; ++r) {
        float m = s[0][r];
#pragma unroll
        for (int nt = 1; nt < 8; ++nt) m = fmaxf(m, s[nt][r]);
        m = fmaxf(m, __shfl_xor(m, 1));
        m = fmaxf(m, __shfl_xor(m, 2));
        m = fmaxf(m, __shfl_xor(m, 4));
        m = fmaxf(m, __shfl_xor(m, 8));
        float sum = 0.f;
#pragma unroll
        for (int nt = 0; nt < 8; ++nt) {
            float e = __expf(s[nt][r] - m);
            p[nt][r] = e;
            sum += e;
        }
        sum += __shfl_xor(sum, 1);
        sum += __shfl_xor(sum, 2);
        sum += __shfl_xor(sum, 4);
        sum += __shfl_xor(sum, 8);
        inv[r] = 1.0f / sum;
    }

    // --- P (unnormalized) -> LDS bf16, rows >=49 zeroed
#pragma unroll
    for (int r = 0; r < 4; ++r) {
        int q = qbase + r;
        bool ok = (q < WS2);
#pragma unroll
        for (int nt = 0; nt < 8; ++nt) {
            short pv = ok ? f2bf(p[nt][r]) : (short)0;
            Pb[q * 128 + (((nt * 2 + (cl >> 3)) ^ (q & 7)) << 3) + (cl & 7)] = pv;
        }
    }
    __syncthreads();

    // --- PV: O[q][d] = P @ V, then apply inv
    f32x4 o0 = {0.f, 0.f, 0.f, 0.f}, o1 = {0.f, 0.f, 0.f, 0.f};
#pragma unroll
    for (int ks = 0; ks < 4; ++ks) {
        short8 pa = *reinterpret_cast<const short8*>(
            Pb + qa * 128 + ((((ks * 4 + kch) ^ (qa & 7))) << 3));
        {
            int d = cl;
            short8 vb = *reinterpret_cast<const short8*>(
                Vt + d * 128 + ((((ks * 4 + kch) ^ (d & 7))) << 3));
            o0 = __builtin_amdgcn_mfma_f32_16x16x32_bf16(pa, vb, o0, 0, 0, 0);
        }
        {
            int d = 16 + cl;
            short8 vb = *reinterpret_cast<const short8*>(
                Vt + d * 128 + ((((ks * 4 + kch) ^ (d & 7))) << 3));
            o1 = __builtin_amdgcn_mfma_f32_16x16x32_bf16(pa, vb, o1, 0, 0, 0);
        }
    }
#pragma unroll
    for (int r = 0; r < 4; ++r) {
        int q = qbase + r;
        if (q < WS2) {
            size_t ob = (((size_t)b * NW + w) * WS2 + q) * 96 + h * 32;
            out[ob + cl]      = f2bf(o0[r] * inv[r]);
            out[ob + 16 + cl] = f2bf(o1[r] * inv[r]);
        }
    }
}

// ---------------- launch ----------------
extern "C" void kernel_launch(void* const* d_in, const int* in_sizes, int n_in,
                              void* d_out, int out_size, void* d_ws, size_t ws_size,
                              hipStream_t stream) {
    const float* x0     = (const float*)d_in[0];
    const float* x1     = (const float*)d_in[1];
    const float* qkv_w  = (const float*)d_in[2];
    const float* qkv_b  = (const float*)d_in[3];
    const float* proj_w = (const float*)d_in[4];
    const float* proj_b = (const float*)d_in[5];
    const float* r0w1   = (const float*)d_in[6];
    const float* r0b1   = (const float*)d_in[7];
    const float* r0w2   = (const float*)d_in[8];
    const float* r0b2   = (const float*)d_in[9];
    const float* r1w1   = (const float*)d_in[10];
    const float* r1b1   = (const float*)d_in[11];
    const float* r1w2   = (const float*)d_in[12];
    const float* r1b2   = (const float*)d_in[13];

    char* ws = (char*)d_ws;
    int*   idx0 = (int*)(ws + OFF_IDX0);
    int*   idx1 = (int*)(ws + OFF_IDX1);
    short* qkv0 = (short*)(ws + OFF_QKV0);
    short* qkv1 = (short*)(ws + OFF_QKV1);
    float* rpb  = (float*)(ws + OFF_RPB);
    short* att  = (short*)(ws + OFF_ATT);
    short* wqb  = (short*)(ws + OFF_WQ);
    short* wpb  = (short*)(ws + OFF_WP);

    build_idx<<<NW, 256, 0, stream>>>(idx0, idx1);
    cvt_weights<<<108, 256, 0, stream>>>(qkv_w, proj_w, wqb, wpb);

    // qkv (fp32 in, bf16 out): M=100352 -> 784 blocks; M=2048 -> 16 blocks
    linear_mfma<3, 8, false, true><<<784, 384, 0, stream>>>(x0, wqb, qkv_b, qkv0);
    linear_mfma<3, 8, false, true><<<16, 384, 0, stream>>>(x1, wqb, qkv_b, qkv1);

    rpb_kernel<<<(NW * WS2 * NKEY + 255) / 256, 256, 0, stream>>>(
        idx0, idx1, r0w1, r0b1, r0w2, r0b2, r1w1, r1b1, r1w2, r1b2, rpb);

    attn_mfma<<<BATCH * NW * HEADS, 256, 0, stream>>>(qkv0, qkv1, idx0, idx1, rpb, att);

    // proj (bf16 in, fp32 out): M=100352 -> 784 blocks
    linear_mfma<1, 8, true, false><<<784, 384, 0, stream>>>(att, wpb, proj_b, (float*)d_out);
}

// Round 10
// 228.223 us; speedup vs baseline: 28.7400x; 1.0267x over previous
//
#include <hip/hip_runtime.h>
#include <hip/hip_bf16.h>
#include <math.h>
#include <limits.h>

#define HEADS 3
#define HD 32
#define WIN 7
#define RESH 56
#define RESW 56
#define TOPK 64
#define NW 64
#define WS2 49
#define NKEY 128
#define BATCH 32
#define NPIX 3136
#define SCALE 0.17677669529663687f

typedef __attribute__((ext_vector_type(8))) short short8;
typedef __attribute__((ext_vector_type(4))) float f32x4;

// ---------------- workspace layout (bytes) ----------------
#define OFF_IDX0 0ull
#define OFF_IDX1 16384ull
#define OFF_QKV0 32768ull                         // 32*3136*288*2 = 57802752
#define OFF_QKV1 57835520ull                      // 32*64*288*2   = 1179648
#define OFF_RPB  59015168ull                      // 64*3*49*128*4 = 4816896
#define OFF_ATT  63832064ull                      // 32*64*49*96*2 = 19267584
#define OFF_WQ   83099648ull                      // 288*96*2
#define OFF_WP   83154944ull                      // 96*96*2

// f32 -> bf16 bits, round-to-nearest-even
__device__ inline short f2bf(float f) {
    unsigned u = __float_as_uint(f);
    unsigned r = (u + 0x7fffu + ((u >> 16) & 1u)) >> 16;
    return (short)r;
}

// ---------------- build neighbor index tables (unchanged) ----------------
__global__ void build_idx(int* __restrict__ idx0, int* __restrict__ idx1) {
    __shared__ int keys[176];
    int w = blockIdx.x;
    int t = threadIdx.x;
    int cqh = 7 * (w >> 3) + 3, cqw = 7 * (w & 7) + 3;

    if (t < 169) {
        int dh = t / 13 - 6, dw = t % 13 - 6;
        int ph = cqh + dh, pw = cqw + dw;
        int k = INT_MAX;
        if (ph >= 0 && ph < RESH && pw >= 0 && pw < RESW)
            k = ((dh * dh + dw * dw) << 12) | (ph * RESW + pw);
        keys[t] = k;
    }
    __syncthreads();
    if (t < 169 && keys[t] != INT_MAX) {
        int my = keys[t];
        int rank = 0;
        for (int j = 0; j < 169; ++j) rank += (keys[j] < my);
        if (rank < TOPK) idx0[w * TOPK + rank] = my & 4095;
    }
    __syncthreads();

    if (t < NW) {
        int kh = 7 * (t >> 3) + 3, kw = 7 * (t & 7) + 3;
        int dh = cqh - kh, dw = cqw - kw;
        keys[t] = ((dh * dh + dw * dw) << 6) | t;
    }
    __syncthreads();
    if (t < NW) {
        int my = keys[t];
        int rank = 0;
        for (int j = 0; j < NW; ++j) rank += (keys[j] < my);
        idx1[w * TOPK + rank] = my & 63;
    }
}

// ---------------- weight conversion f32 -> bf16 ----------------
__global__ void cvt_weights(const float* __restrict__ qkv_w,
                            const float* __restrict__ proj_w,
                            short* __restrict__ wq, short* __restrict__ wp) {
    int i = blockIdx.x * 256 + threadIdx.x;
    if (i < 288 * 96) wq[i] = f2bf(qkv_w[i]);
    if (i < 96 * 96)  wp[i] = f2bf(proj_w[i]);
}

// ---------------- MFMA linear (templated on in/out dtype) ----------------
// y[M][NOUT] = x[M][96] @ w^T + b. 6 waves, B-frags resident in VGPRs,
// zero LDS / zero barriers. MT=2 -> 4x more blocks than round 9 (occupancy
// was grid-capped at ~1.5 waves/SIMD; latency-bound counters r9).
template <int NT, int MT, bool INBF, bool OUTBF>
__global__ __launch_bounds__(384) void linear_mfma(const void* __restrict__ xv,
                                                   const short* __restrict__ wb,
                                                   const float* __restrict__ bias,
                                                   void* __restrict__ yv) {
    const int NOUT = 96 * NT;
    const float* xf = (const float*)xv;
    const short* xb = (const short*)xv;
    float* yf = (float*)yv;
    short* yb = (short*)yv;
    int wv = threadIdx.x >> 6;
    int l  = threadIdx.x & 63;
    int cl = l & 15;
    int kch = l >> 4;
    int n0 = wv * 16 * NT;

    short8 bfr[NT][3];
    float bv[NT];
#pragma unroll
    for (int nt = 0; nt < NT; ++nt) {
        int n = n0 + nt * 16 + cl;
        bv[nt] = bias[n];
#pragma unroll
        for (int ks = 0; ks < 3; ++ks)
            bfr[nt][ks] = *reinterpret_cast<const short8*>(wb + n * 96 + ks * 32 + kch * 8);
    }

    size_t m0 = (size_t)blockIdx.x * (MT * 16);
#pragma unroll
    for (int mt = 0; mt < MT; ++mt) {
        size_t mrow = m0 + mt * 16 + cl;
        short8 af[3];
        if constexpr (INBF) {
            const short* xp = xb + mrow * 96 + kch * 8;
#pragma unroll
            for (int ks = 0; ks < 3; ++ks)
                af[ks] = *reinterpret_cast<const short8*>(xp + ks * 32);
        } else {
            const float* xp = xf + mrow * 96 + kch * 8;
#pragma unroll
            for (int ks = 0; ks < 3; ++ks) {
                float4 u0 = *reinterpret_cast<const float4*>(xp + ks * 32);
                float4 u1 = *reinterpret_cast<const float4*>(xp + ks * 32 + 4);
                short8 a;
                a[0] = f2bf(u0.x); a[1] = f2bf(u0.y); a[2] = f2bf(u0.z); a[3] = f2bf(u0.w);
                a[4] = f2bf(u1.x); a[5] = f2bf(u1.y); a[6] = f2bf(u1.z); a[7] = f2bf(u1.w);
                af[ks] = a;
            }
        }
#pragma unroll
        for (int nt = 0; nt < NT; ++nt) {
            f32x4 acc = {bv[nt], bv[nt], bv[nt], bv[nt]};
#pragma unroll
            for (int ks = 0; ks < 3; ++ks)
                acc = __builtin_amdgcn_mfma_f32_16x16x32_bf16(af[ks], bfr[nt][ks], acc, 0, 0, 0);
            size_t rb = m0 + mt * 16 + kch * 4;
            int c = n0 + nt * 16 + cl;
#pragma unroll
            for (int r = 0; r < 4; ++r) {
                if constexpr (OUTBF) yb[(rb + r) * NOUT + c] = f2bf(acc[r]);
                else                 yf[(rb + r) * NOUT + c] = acc[r];
            }
        }
    }
}

// ---------------- relative position bias MLP (unchanged) ----------------
__global__ void rpb_kernel(const int* __restrict__ idx0, const int* __restrict__ idx1,
                           const float* __restrict__ w1_0, const float* __restrict__ b1_0,
                           const float* __restrict__ w2_0, const float* __restrict__ b2_0,
                           const float* __restrict__ w1_1, const float* __restrict__ b1_1,
                           const float* __restrict__ w2_1, const float* __restrict__ b2_1,
                           float* __restrict__ rpb) {
    int gid = blockIdx.x * blockDim.x + threadIdx.x;
    if (gid >= NW * WS2 * NKEY) return;
    int t = gid & 127;
    int q = (gid >> 7) % WS2;
    int w = gid / (WS2 * NKEY);

    int qph = 7 * (w >> 3) + q / 7;
    int qpw = 7 * (w & 7) + q % 7;

    int ckh, ckw;
    const float *w1, *b1, *w2, *b2;
    if (t < TOPK) {
        int p = idx0[w * TOPK + t];
        ckh = p / RESW; ckw = p % RESW;
        w1 = w1_0; b1 = b1_0; w2 = w2_0; b2 = b2_0;
    } else {
        int p = idx1[w * TOPK + (t - TOPK)];
        ckh = 7 * (p >> 3) + 3; ckw = 7 * (p & 7) + 3;
        w1 = w1_1; b1 = b1_1; w2 = w2_1; b2 = b2_1;
    }
    float fh = (float)(qph - ckh) / 56.0f;
    float fw = (float)(qpw - ckw) / 56.0f;

    float o0 = b2[0], o1 = b2[1], o2 = b2[2];
#pragma unroll
    for (int d = 0; d < HD; ++d) {
        float hd = fmaf(w1[d * 2], fh, fmaf(w1[d * 2 + 1], fw, b1[d]));
        hd = fmaxf(hd, 0.0f);
        o0 = fmaf(w2[d], hd, o0);
        o1 = fmaf(w2[HD + d], hd, o1);
        o2 = fmaf(w2[2 * HD + d], hd, o2);
    }
    int base = ((w * HEADS + 0) * WS2 + q) * NKEY + t;
    rpb[base] = o0;
    rpb[base + WS2 * NKEY] = o1;
    rpb[base + 2 * WS2 * NKEY] = o2;
}

// ---------------- attention v3: full MFMA (unchanged, r9-validated) --------
__global__ __launch_bounds__(256) void attn_mfma(
        const short* __restrict__ qkv0, const short* __restrict__ qkv1,
        const int* __restrict__ idx0, const int* __restrict__ idx1,
        const float* __restrict__ rpb, short* __restrict__ out) {
    __shared__ __align__(16) short Qb[64 * 32];    // 4 KB, chunk-rotated
    __shared__ __align__(16) short Kb[128 * 32];   // 8 KB, chunk-rotated
    __shared__ __align__(16) short Vt[32 * 128];   // 8 KB, transposed + XOR swz
    __shared__ __align__(16) short Pb[64 * 128];   // 16 KB, XOR swz

    int blk = blockIdx.x;                 // ((b*64)+w)*3+h
    int h = blk % HEADS;
    int w = (blk / HEADS) & 63;
    int b = blk / (HEADS * NW);
    int tid = threadIdx.x;
    int wv = tid >> 6, l = tid & 63;
    int cl = l & 15, kch = l >> 4;
    int wi = w >> 3, wj = w & 7;

    // --- stage Q (64 rows x 4 chunks; rows >=49 zero)
    {
        int q = tid >> 2, c = tid & 3;
        short8 v = {0, 0, 0, 0, 0, 0, 0, 0};
        if (q < WS2) {
            int pix = (wi * 7 + q / 7) * RESW + wj * 7 + q % 7;
            v = *reinterpret_cast<const short8*>(
                qkv0 + ((size_t)b * NPIX + pix) * 288 + h * 32 + c * 8);
        }
        *reinterpret_cast<short8*>(Qb + q * 32 + (((c + (q >> 1)) & 3) << 3)) = v;
    }
    // --- stage K (c-fast: coalesced global, rotate-swizzled LDS)
#pragma unroll
    for (int i = 0; i < 2; ++i) {
        int u = tid + 256 * i;
        int k = u >> 2, c = u & 3;
        const short* src = (k < TOPK)
            ? qkv0 + ((size_t)b * NPIX + idx0[w * TOPK + k]) * 288 + 96 + h * 32
            : qkv1 + ((size_t)b * NW + idx1[w * TOPK + k - TOPK]) * 288 + 96 + h * 32;
        short8 kv = *reinterpret_cast<const short8*>(src + c * 8);
        *reinterpret_cast<short8*>(Kb + k * 32 + (((c + (k >> 1)) & 3) << 3)) = kv;
    }
    // --- stage V transposed (k-fast keeps the b16 scatter <=2-way)
#pragma unroll
    for (int i = 0; i < 2; ++i) {
        int u = tid + 256 * i;
        int k = u & 127, c = u >> 7;
        const short* src = (k < TOPK)
            ? qkv0 + ((size_t)b * NPIX + idx0[w * TOPK + k]) * 288 + 192 + h * 32
            : qkv1 + ((size_t)b * NW + idx1[w * TOPK + k - TOPK]) * 288 + 192 + h * 32;
        short8 vv = *reinterpret_cast<const short8*>(src + c * 8);
#pragma unroll
        for (int jj = 0; jj < 8; ++jj) {
            int d = c * 8 + jj;
            Vt[d * 128 + (((k >> 3) ^ (d & 7)) << 3) + (k & 7)] = vv[jj];
        }
    }
    // --- rpb into registers (coalesced fp32 reads)
    const float* rp = rpb + (size_t)(w * HEADS + h) * WS2 * NKEY;
    int qbase = wv * 16 + kch * 4;
    float rv[8][4];
#pragma unroll
    for (int nt = 0; nt < 8; ++nt)
#pragma unroll
        for (int r = 0; r < 4; ++r) {
            int q = qbase + r;
            rv[nt][r] = (q < WS2) ? rp[q * NKEY + nt * 16 + cl] : 0.0f;
        }
    __syncthreads();

    // --- QK^T: S[q][key], q-tile wv
    int qa = wv * 16 + cl;
    short8 qf = *reinterpret_cast<const short8*>(
        Qb + qa * 32 + (((kch + (qa >> 1)) & 3) << 3));
    float s[8][4];
#pragma unroll
    for (int nt = 0; nt < 8; ++nt) {
        int key = nt * 16 + cl;
        short8 kf = *reinterpret_cast<const short8*>(
            Kb + key * 32 + (((kch + (key >> 1)) & 3) << 3));
        f32x4 a = {0.f, 0.f, 0.f, 0.f};
        a = __builtin_amdgcn_mfma_f32_16x16x32_bf16(qf, kf, a, 0, 0, 0);
#pragma unroll
        for (int r = 0; r < 4; ++r) s[nt][r] = fmaf(a[r], SCALE, rv[nt][r]);
    }

    // --- in-register softmax over 128 keys (rows q = qbase + r)
    float inv[4], p[8][4];
#pragma unroll
    for (int r = 0; r < 4; ++r) {
        float m = s[0][r];
#pragma unroll
        for (int nt = 1; nt < 8; ++nt) m = fmaxf(m, s[nt][r]);
        m = fmaxf(m, __shfl_xor(m, 1));
        m = fmaxf(m, __shfl_xor(m, 2));
        m = fmaxf(m, __shfl_xor(m, 4));
        m = fmaxf(m, __shfl_xor(m, 8));
        float sum = 0.f;
#pragma unroll
        for (int nt = 0; nt < 8; ++nt) {
            float e = __expf(s[nt][r] - m);
            p[nt][r] = e;
            sum += e;
        }
        sum += __shfl_xor(sum, 1);
        sum += __shfl_xor(sum, 2);
        sum += __shfl_xor(sum, 4);
        sum += __shfl_xor(sum, 8);
        inv[r] = 1.0f / sum;
    }

    // --- P (unnormalized) -> LDS bf16, rows >=49 zeroed
#pragma unroll
    for (int r = 0; r < 4; ++r) {
        int q = qbase + r;
        bool ok = (q < WS2);
#pragma unroll
        for (int nt = 0; nt < 8; ++nt) {
            short pv = ok ? f2bf(p[nt][r]) : (short)0;
            Pb[q * 128 + (((nt * 2 + (cl >> 3)) ^ (q & 7)) << 3) + (cl & 7)] = pv;
        }
    }
    __syncthreads();

    // --- PV: O[q][d] = P @ V, then apply inv
    f32x4 o0 = {0.f, 0.f, 0.f, 0.f}, o1 = {0.f, 0.f, 0.f, 0.f};
#pragma unroll
    for (int ks = 0; ks < 4; ++ks) {
        short8 pa = *reinterpret_cast<const short8*>(
            Pb + qa * 128 + ((((ks * 4 + kch) ^ (qa & 7))) << 3));
        {
            int d = cl;
            short8 vb = *reinterpret_cast<const short8*>(
                Vt + d * 128 + ((((ks * 4 + kch) ^ (d & 7))) << 3));
            o0 = __builtin_amdgcn_mfma_f32_16x16x32_bf16(pa, vb, o0, 0, 0, 0);
        }
        {
            int d = 16 + cl;
            short8 vb = *reinterpret_cast<const short8*>(
                Vt + d * 128 + ((((ks * 4 + kch) ^ (d & 7))) << 3));
            o1 = __builtin_amdgcn_mfma_f32_16x16x32_bf16(pa, vb, o1, 0, 0, 0);
        }
    }
#pragma unroll
    for (int r = 0; r < 4; ++r) {
        int q = qbase + r;
        if (q < WS2) {
            size_t ob = (((size_t)b * NW + w) * WS2 + q) * 96 + h * 32;
            out[ob + cl]      = f2bf(o0[r] * inv[r]);
            out[ob + 16 + cl] = f2bf(o1[r] * inv[r]);
        }
    }
}

// ---------------- launch ----------------
extern "C" void kernel_launch(void* const* d_in, const int* in_sizes, int n_in,
                              void* d_out, int out_size, void* d_ws, size_t ws_size,
                              hipStream_t stream) {
    const float* x0     = (const float*)d_in[0];
    const float* x1     = (const float*)d_in[1];
    const float* qkv_w  = (const float*)d_in[2];
    const float* qkv_b  = (const float*)d_in[3];
    const float* proj_w = (const float*)d_in[4];
    const float* proj_b = (const float*)d_in[5];
    const float* r0w1   = (const float*)d_in[6];
    const float* r0b1   = (const float*)d_in[7];
    const float* r0w2   = (const float*)d_in[8];
    const float* r0b2   = (const float*)d_in[9];
    const float* r1w1   = (const float*)d_in[10];
    const float* r1b1   = (const float*)d_in[11];
    const float* r1w2   = (const float*)d_in[12];
    const float* r1b2   = (const float*)d_in[13];

    char* ws = (char*)d_ws;
    int*   idx0 = (int*)(ws + OFF_IDX0);
    int*   idx1 = (int*)(ws + OFF_IDX1);
    short* qkv0 = (short*)(ws + OFF_QKV0);
    short* qkv1 = (short*)(ws + OFF_QKV1);
    float* rpb  = (float*)(ws + OFF_RPB);
    short* att  = (short*)(ws + OFF_ATT);
    short* wqb  = (short*)(ws + OFF_WQ);
    short* wpb  = (short*)(ws + OFF_WP);

    build_idx<<<NW, 256, 0, stream>>>(idx0, idx1);
    cvt_weights<<<108, 256, 0, stream>>>(qkv_w, proj_w, wqb, wpb);

    // qkv (fp32 in, bf16 out): MT=2 -> 32 rows/block (occupancy: r9 was
    // grid-capped at ~1.5 waves/SIMD; 3136 blocks -> ~5 blocks/CU resident)
    linear_mfma<3, 2, false, true><<<3136, 384, 0, stream>>>(x0, wqb, qkv_b, qkv0);
    linear_mfma<3, 2, false, true><<<64, 384, 0, stream>>>(x1, wqb, qkv_b, qkv1);

    rpb_kernel<<<(NW * WS2 * NKEY + 255) / 256, 256, 0, stream>>>(
        idx0, idx1, r0w1, r0b1, r0w2, r0b2, r1w1, r1b1, r1w2, r1b2, rpb);

    attn_mfma<<<BATCH * NW * HEADS, 256, 0, stream>>>(qkv0, qkv1, idx0, idx1, rpb, att);

    // proj (bf16 in, fp32 out): MT=2 -> 3136 blocks
    linear_mfma<1, 2, true, false><<<3136, 384, 0, stream>>>(att, wpb, proj_b, (float*)d_out);
}